// Round 6
// baseline (491.604 us; speedup 1.0000x reference)
//
#include <hip/hip_runtime.h>
#include <hip/hip_cooperative_groups.h>
#include <cstdint>
#include <cstddef>

namespace cg = cooperative_groups;

using u16 = unsigned short;
using u32 = unsigned int;

typedef __attribute__((ext_vector_type(8))) short bf16x8;   // 8 bf16 = 4 VGPRs
typedef __attribute__((ext_vector_type(16))) float f32x16;  // MFMA 32x32 acc

__device__ __forceinline__ u16 f2bf(float f) {  // round-to-nearest-even
  union { float f; u32 i; } x; x.f = f;
  u32 r = (x.i + 0x7FFFu + ((x.i >> 16) & 1u)) >> 16;
  return (u16)r;
}
__device__ __forceinline__ bf16x8 ldbf16x8(const u16* p) {
  union { uint4 u; bf16x8 v; } t;
  t.u = *(const uint4*)p;
  return t.v;
}

// Geometry: x (16,32,128,128) fp32 -> G=2 groups, F=256 features/group,
// N=16384 positions, 8 heads/group, dim_head=64.  Collapse:
// C[g]=F·F^T Gram; sim=Wq_h·C·Wk_h^T; attn=softmax; M=(Wout·bd(attn))·Wv;
// out = M·f + bout.
constexpr int NP = 16384;

// Fragment-tiled bf16 layouts: element (row, k) lives at
//   [panel=row>>5][s=k>>4][h=(k>>3)&1][lc=row&31][j=k&7]
// XbF  : rows=256 f,  k=16384 p   -> panel stride 524288
// XbTF : rows=16384 p, k=256 f    -> panel stride 8192
// MAF  : rows=256 co, k=256 f(=b) -> panel stride 8192

// ws layout (fp32 element offsets)
constexpr size_t OFF_C   = 0;        // C[2][256][256]        131072
constexpr size_t OFF_T   = 131072;   // T (fallback)          262144
constexpr size_t OFF_AT  = 393216;   // sim/attn[16][64][64]   65536
constexpr size_t OFF_WE  = 458752;   // WeT (fallback)        262144
constexpr size_t OFF_MT  = 720896;   // Mt (fallback)         131072
constexpr size_t OFF_MA  = 851968;   // MAF bf16 [2][...]     (65536 fl)
constexpr size_t OFF_XB  = 917504;   // XbF  bf16 [2][...]    (4194304 fl)
constexpr size_t OFF_XBT = 5111808;  // XbTF bf16 [2][...]    (4194304 fl)
constexpr size_t OFF_CP1 = 9306112;  // Cpart1 [2][4tp][32kc][16384] (4194304)
                                     // reused as Mp[2][8h][256co][256b]
constexpr size_t NEED1   = (OFF_CP1 + 4194304 + 4) * 4;  // ~54.0 MB
constexpr size_t OFF_CP2 = 851968;   // fp32-fallback partials (6291456 fl)
constexpr size_t NEED2   = (OFF_CP2 + 6291456) * 4;  // 28,573,696 B

// ---------------------------------------------------------------------------
// Fused mfma path: all 7 phases in one cooperative kernel, 512 blocks.
// grid.sync() (cooperative launch) guarantees co-residency -> no deadlock.
__global__ __launch_bounds__(256, 2)
void fused_all(const float* __restrict__ x, const float* __restrict__ Wq,
               const float* __restrict__ Wkv, const float* __restrict__ Wout,
               const float* __restrict__ bout, float* __restrict__ out,
               u16* __restrict__ XbF, u16* __restrict__ XbTF,
               float* __restrict__ Cmat, float* __restrict__ attn,
               u16* __restrict__ MA, float* __restrict__ Cpart) {
  __shared__ __align__(16) u32 shm[256 * 33];   // 33 KB union for all phases
  cg::grid_group grid = cg::this_grid();
  const int bid = blockIdx.x;
  const int tid = threadIdx.x;

  // ======== P0: k0 convert — x fp32 -> XbF + XbTF (1 slab per block) =======
  {
    const int pc = bid >> 1, g = bid & 1;
    const int p0 = pc * 64;
    const float* __restrict__ Xg = x + (size_t)g * 256 * NP;
    u16* __restrict__ XbFg  = XbF  + (size_t)g * 256 * NP;
    u16* __restrict__ XbTFg = XbTF + (size_t)g * NP * 256;
    const int f8i = tid & 7, rb = tid >> 3;
    const int sA = pc * 4 + (f8i >> 1);
    const int hA = f8i & 1;
    u32* Fs = shm;
    for (int pass = 0; pass < 8; ++pass) {
      const int row = rb + pass * 32;
      const size_t e0 = (size_t)row * NP + p0 + f8i * 8;
      float4 a = *(const float4*)(Xg + e0);
      float4 b = *(const float4*)(Xg + e0 + 4);
      const float v[8] = {a.x, a.y, a.z, a.w, b.x, b.y, b.z, b.w};
      uint4 s;
      s.x = (u32)f2bf(v[0]) | ((u32)f2bf(v[1]) << 16);
      s.y = (u32)f2bf(v[2]) | ((u32)f2bf(v[3]) << 16);
      s.z = (u32)f2bf(v[4]) | ((u32)f2bf(v[5]) << 16);
      s.w = (u32)f2bf(v[6]) | ((u32)f2bf(v[7]) << 16);
      const int panel = row >> 5, lc = row & 31;
      *(uint4*)(XbFg + (size_t)panel * 524288 + sA * 512 + hA * 256 + lc * 8) =
          s;
      u32* d = &Fs[row * 33 + f8i * 4];
      d[0] = s.x; d[1] = s.y; d[2] = s.z; d[3] = s.w;
    }
    __syncthreads();
    const int p = tid & 63, grp = tid >> 6;
    const int pp = p0 + p;
    const int panelT = pp >> 5, lcT = pp & 31;
    const u16* __restrict__ Fs16 = (const u16*)Fs;
    u16* dstT = XbTFg + (size_t)panelT * 8192 + lcT * 8;
    for (int c = 0; c < 4; ++c) {
      const int sT = grp * 4 + c;
      u32 w[8];
#pragma unroll
      for (int q = 0; q < 8; ++q) {
        const int f = grp * 64 + c * 16 + q * 2;
        u32 lo = Fs16[f * 66 + p];
        u32 hi = Fs16[(f + 1) * 66 + p];
        w[q] = lo | (hi << 16);
      }
      uint4 s0 = {w[0], w[1], w[2], w[3]};
      uint4 s1 = {w[4], w[5], w[6], w[7]};
      *(uint4*)(dstT + sT * 512)       = s0;
      *(uint4*)(dstT + sT * 512 + 256) = s1;
    }
  }
  grid.sync();

  // ======== P1: k1 Gram partials (128x128 tiles, 256 active blocks) ========
  if (bid < 256) {
    const int tp = bid >> 6, kc = (bid >> 1) & 31, g = bid & 1;
    const int ti = tp >> 1, tj = tp & 1;
    const int w = tid >> 6, half = (tid >> 5) & 1, lc = tid & 31;
    const int qi = w >> 1, qj = w & 1;
    const u16* __restrict__ Xg = XbF + (size_t)g * 256 * NP;
    const size_t koff = (size_t)kc * 16384 + half * 256 + lc * 8;
    const u16* A0 = Xg + (size_t)(ti * 4 + qi * 2 + 0) * 524288 + koff;
    const u16* A1 = Xg + (size_t)(ti * 4 + qi * 2 + 1) * 524288 + koff;
    const u16* B0 = Xg + (size_t)(tj * 4 + qj * 2 + 0) * 524288 + koff;
    const u16* B1 = Xg + (size_t)(tj * 4 + qj * 2 + 1) * 524288 + koff;
    f32x16 acc00, acc01, acc10, acc11;
#pragma unroll
    for (int i = 0; i < 16; ++i) {
      acc00[i] = 0.f; acc01[i] = 0.f; acc10[i] = 0.f; acc11[i] = 0.f;
    }
#pragma unroll 4
    for (int s = 0; s < 32; ++s) {
      bf16x8 a0 = ldbf16x8(A0 + s * 512);
      bf16x8 a1 = ldbf16x8(A1 + s * 512);
      bf16x8 b0 = ldbf16x8(B0 + s * 512);
      bf16x8 b1 = ldbf16x8(B1 + s * 512);
      acc00 = __builtin_amdgcn_mfma_f32_32x32x16_bf16(a0, b0, acc00, 0, 0, 0);
      acc01 = __builtin_amdgcn_mfma_f32_32x32x16_bf16(a0, b1, acc01, 0, 0, 0);
      acc10 = __builtin_amdgcn_mfma_f32_32x32x16_bf16(a1, b0, acc10, 0, 0, 0);
      acc11 = __builtin_amdgcn_mfma_f32_32x32x16_bf16(a1, b1, acc11, 0, 0, 0);
    }
    float* __restrict__ P = Cpart + (((size_t)g * 4 + tp) * 32 + kc) * 16384;
#pragma unroll
    for (int r = 0; r < 16; ++r) {
      const int rr = (r & 3) + 8 * (r >> 2) + 4 * half;
      const int row0 = qi * 64 + rr, col0 = qj * 64 + lc;
      P[(row0 +  0) * 128 + col0 +  0] = acc00[r];
      P[(row0 +  0) * 128 + col0 + 32] = acc01[r];
      P[(row0 + 32) * 128 + col0 +  0] = acc10[r];
      P[(row0 + 32) * 128 + col0 + 32] = acc11[r];
    }
  }
  grid.sync();

  // ======== P2: k1b reduce partials -> C (512 blocks) ========
  {
    const int sl = bid >> 3, tp = (bid >> 1) & 3, g = bid & 1;
    const int ele = sl * 256 + tid;
    const float* __restrict__ P =
        Cpart + (((size_t)g * 4 + tp) * 32) * 16384 + ele;
    float v = 0.f;
#pragma unroll
    for (int kc = 0; kc < 32; ++kc) v += P[(size_t)kc * 16384];
    const int ti = tp >> 1, tj = tp & 1;
    const int i = ele >> 7, j = ele & 127;
    Cmat[(size_t)g * 65536 + (size_t)(ti * 128 + i) * 256 + tj * 128 + j] = v;
  }
  grid.sync();

  // ======== P3: kA fused T/sim/softmax (256 active blocks) ========
  if (bid < 256) {
    float* WqL = (float*)shm;          // 1024 floats
    float* Ts  = (float*)shm + 1024;   // 1024 floats
    const int bh = bid >> 4, ic = bid & 15;
    const int g = bh >> 3, hh = bh & 7;
    const float* __restrict__ Cg = Cmat + (size_t)g * 65536;
    {
      const int r = tid >> 6, c4 = (tid & 63) * 4;
      *(float4*)(&WqL[r * 256 + c4]) =
          *(const float4*)(Wq + (size_t)(hh * 64 + ic * 4 + r) * 256 + c4);
    }
    __syncthreads();
    float acc[4] = {0.f, 0.f, 0.f, 0.f};
#pragma unroll 8
    for (int b = 0; b < 256; ++b) {
      const float cv = Cg[(size_t)b * 256 + tid];
#pragma unroll
      for (int r = 0; r < 4; ++r) acc[r] += WqL[r * 256 + b] * cv;
    }
#pragma unroll
    for (int r = 0; r < 4; ++r) Ts[r * 256 + tid] = acc[r];
    __syncthreads();
    const int r = tid >> 6, j = tid & 63;
    const float* __restrict__ Wk = Wkv + (size_t)(hh * 64 + j) * 256;
    float s = 0.f;
#pragma unroll 4
    for (int a4 = 0; a4 < 64; ++a4) {
      float4 w = *(const float4*)(Wk + a4 * 4);
      const float* t4 = &Ts[r * 256 + a4 * 4];
      s += t4[0] * w.x + t4[1] * w.y + t4[2] * w.z + t4[3] * w.w;
    }
    s *= 0.125f;
    float m = s;
#pragma unroll
    for (int off = 32; off; off >>= 1) m = fmaxf(m, __shfl_xor(m, off));
    const float e = __expf(s - m);
    float sum = e;
#pragma unroll
    for (int off = 32; off; off >>= 1) sum += __shfl_xor(sum, off);
    attn[((size_t)bh * 64 + ic * 4 + r) * 64 + j] = e / sum;
  }
  grid.sync();

  // ======== P4: kB fused Wout·attn then ·Wv -> Mp (256 active blocks) ======
  if (bid < 256) {
    float* AtL = (float*)shm;          // 4096 floats
    float* WoL = (float*)shm + 4096;   // 1024 floats
    float* UL  = (float*)shm + 5120;   // 1024 floats
    const int bh = bid >> 4, cc = bid & 15;
    const int g = bh >> 3, hh = bh & 7;
    {
      const float* __restrict__ A = attn + (size_t)bh * 4096;
#pragma unroll
      for (int q = 0; q < 4; ++q)
        *(float4*)(&AtL[q * 1024 + tid * 4]) =
            *(const float4*)(A + q * 1024 + tid * 4);
    }
    {
      const int co_l = tid >> 4, i4 = (tid & 15) * 4;
      *(float4*)(&WoL[co_l * 64 + i4]) = *(const float4*)(
          Wout + (size_t)(cc * 16 + co_l) * 512 + hh * 64 + i4);
    }
    __syncthreads();
    const int j = tid & 63, cw = tid >> 6;
    float u4[4] = {0.f, 0.f, 0.f, 0.f};
#pragma unroll 4
    for (int i = 0; i < 64; ++i) {
      const float av = AtL[i * 64 + j];
#pragma unroll
      for (int u = 0; u < 4; ++u) u4[u] += WoL[(cw * 4 + u) * 64 + i] * av;
    }
    __syncthreads();
#pragma unroll
    for (int u = 0; u < 4; ++u) UL[(cw * 4 + u) * 64 + j] = u4[u];
    __syncthreads();
    float acc[16];
#pragma unroll
    for (int c = 0; c < 16; ++c) acc[c] = 0.f;
#pragma unroll 4
    for (int j2 = 0; j2 < 64; ++j2) {
      const float wv = Wkv[(size_t)(512 + hh * 64 + j2) * 256 + tid];
#pragma unroll
      for (int c = 0; c < 16; ++c) acc[c] += UL[c * 64 + j2] * wv;
    }
    float* __restrict__ P =
        Cpart + (((size_t)g * 8 + hh) * 256 + cc * 16) * 256 + tid;
#pragma unroll
    for (int c = 0; c < 16; ++c) P[(size_t)c * 256] = acc[c];
  }
  grid.sync();

  // ======== P5: kC reduce heads -> MAF bf16 (64 active blocks) ========
  if (bid < 64) {
    const int xx = bid >> 1, g = bid & 1;
    const int panel = xx >> 2, q = xx & 3;
    const float* __restrict__ Pg = Cpart + (size_t)g * 8 * 65536;
    u16* __restrict__ Mg = MA + (size_t)g * 65536;
    const int item = tid + q * 256;
    const int lc = item & 31;
    const int co = panel * 32 + lc;
    const int b0 = (item >> 5) * 8;
    float v[8] = {0.f, 0.f, 0.f, 0.f, 0.f, 0.f, 0.f, 0.f};
#pragma unroll
    for (int hd = 0; hd < 8; ++hd) {
      const float* p = Pg + (size_t)hd * 65536 + (size_t)co * 256 + b0;
      float4 a = *(const float4*)(p);
      float4 b = *(const float4*)(p + 4);
      v[0] += a.x; v[1] += a.y; v[2] += a.z; v[3] += a.w;
      v[4] += b.x; v[5] += b.y; v[6] += b.z; v[7] += b.w;
    }
    uint4 sdat;
    sdat.x = (u32)f2bf(v[0]) | ((u32)f2bf(v[1]) << 16);
    sdat.y = (u32)f2bf(v[2]) | ((u32)f2bf(v[3]) << 16);
    sdat.z = (u32)f2bf(v[4]) | ((u32)f2bf(v[5]) << 16);
    sdat.w = (u32)f2bf(v[6]) | ((u32)f2bf(v[7]) << 16);
    *(uint4*)(Mg + (size_t)panel * 8192 + (size_t)item * 8) = sdat;
  }
  grid.sync();

  // ======== P6: k6 out = XbT·M^T + bout (512 blocks) ========
  {
    const int pb = bid >> 2, cb = (bid >> 1) & 1, g = bid & 1;
    const int w = tid >> 6, half = (tid >> 5) & 1, lc = tid & 31;
    const int p0  = pb * 128 + w * 32;
    const int co0 = cb * 128;
    const u16* __restrict__ Ap = XbTF + (size_t)g * NP * 256 +
                                 (size_t)(pb * 4 + w) * 8192 + half * 256 +
                                 lc * 8;
    const u16* __restrict__ Bp =
        MA + (size_t)g * 65536 + (size_t)cb * 32768 + half * 256 + lc * 8;
    f32x16 acc[4];
#pragma unroll
    for (int t = 0; t < 4; ++t)
#pragma unroll
      for (int i = 0; i < 16; ++i) acc[t][i] = 0.f;
#pragma unroll 2
    for (int s = 0; s < 16; ++s) {
      bf16x8 a = ldbf16x8(Ap + s * 512);
#pragma unroll
      for (int t = 0; t < 4; ++t) {
        bf16x8 b = ldbf16x8(Bp + (size_t)t * 8192 + s * 512);
        acc[t] = __builtin_amdgcn_mfma_f32_32x32x16_bf16(a, b, acc[t], 0, 0, 0);
      }
    }
#pragma unroll
    for (int t = 0; t < 4; ++t) {
      const int co = co0 + t * 32 + lc;
      const float bo = bout[co];
      float* __restrict__ ocol =
          out + ((size_t)(g * 256 + co)) * NP + p0 + 4 * half;
#pragma unroll
      for (int rg = 0; rg < 4; ++rg) {
        float4 v = {acc[t][rg * 4 + 0] + bo, acc[t][rg * 4 + 1] + bo,
                    acc[t][rg * 4 + 2] + bo, acc[t][rg * 4 + 3] + bo};
        *(float4*)(ocol + rg * 8) = v;
      }
    }
  }
}

// ---------------------------------------------------------------------------
// R4 standalone kernels (fallback if cooperative launch unavailable).
__global__ __launch_bounds__(256)
void k0_cvt(const float* __restrict__ x, u16* __restrict__ XbF,
            u16* __restrict__ XbTF) {
  __shared__ u32 Fs[256 * 33];
  const int pc = blockIdx.x;
  const int g  = blockIdx.y;
  const int p0 = pc * 64;
  const float* __restrict__ Xg = x + (size_t)g * 256 * NP;
  u16* __restrict__ XbFg  = XbF  + (size_t)g * 256 * NP;
  u16* __restrict__ XbTFg = XbTF + (size_t)g * NP * 256;
  const int tid = threadIdx.x;
  const int f8i = tid & 7, rb = tid >> 3;
  const int sA = pc * 4 + (f8i >> 1);
  const int hA = f8i & 1;
  for (int pass = 0; pass < 8; ++pass) {
    const int row = rb + pass * 32;
    const size_t e0 = (size_t)row * NP + p0 + f8i * 8;
    float4 a = *(const float4*)(Xg + e0);
    float4 b = *(const float4*)(Xg + e0 + 4);
    const float v[8] = {a.x, a.y, a.z, a.w, b.x, b.y, b.z, b.w};
    uint4 s;
    s.x = (u32)f2bf(v[0]) | ((u32)f2bf(v[1]) << 16);
    s.y = (u32)f2bf(v[2]) | ((u32)f2bf(v[3]) << 16);
    s.z = (u32)f2bf(v[4]) | ((u32)f2bf(v[5]) << 16);
    s.w = (u32)f2bf(v[6]) | ((u32)f2bf(v[7]) << 16);
    const int panel = row >> 5, lc = row & 31;
    *(uint4*)(XbFg + (size_t)panel * 524288 + sA * 512 + hA * 256 + lc * 8) = s;
    u32* d = &Fs[row * 33 + f8i * 4];
    d[0] = s.x; d[1] = s.y; d[2] = s.z; d[3] = s.w;
  }
  __syncthreads();
  const int p = tid & 63, grp = tid >> 6;
  const int pp = p0 + p;
  const int panelT = pp >> 5, lcT = pp & 31;
  const u16* __restrict__ Fs16 = (const u16*)Fs;
  u16* dstT = XbTFg + (size_t)panelT * 8192 + lcT * 8;
  for (int c = 0; c < 4; ++c) {
    const int sT = grp * 4 + c;
    u32 w[8];
#pragma unroll
    for (int q = 0; q < 8; ++q) {
      const int f = grp * 64 + c * 16 + q * 2;
      u32 lo = Fs16[f * 66 + p];
      u32 hi = Fs16[(f + 1) * 66 + p];
      w[q] = lo | (hi << 16);
    }
    uint4 s0 = {w[0], w[1], w[2], w[3]};
    uint4 s1 = {w[4], w[5], w[6], w[7]};
    *(uint4*)(dstT + sT * 512)       = s0;
    *(uint4*)(dstT + sT * 512 + 256) = s1;
  }
}

__global__ __launch_bounds__(256)
void k1_mfma(const u16* __restrict__ XbF, float* __restrict__ Cpart) {
  const int tp = blockIdx.x;
  const int kc = blockIdx.y;
  const int g  = blockIdx.z;
  const int ti = tp >> 1, tj = tp & 1;
  const int tid = threadIdx.x;
  const int w = tid >> 6, half = (tid >> 5) & 1, lc = tid & 31;
  const int qi = w >> 1, qj = w & 1;
  const u16* __restrict__ Xg = XbF + (size_t)g * 256 * NP;
  const size_t koff = (size_t)kc * 16384 + half * 256 + lc * 8;
  const u16* A0 = Xg + (size_t)(ti * 4 + qi * 2 + 0) * 524288 + koff;
  const u16* A1 = Xg + (size_t)(ti * 4 + qi * 2 + 1) * 524288 + koff;
  const u16* B0 = Xg + (size_t)(tj * 4 + qj * 2 + 0) * 524288 + koff;
  const u16* B1 = Xg + (size_t)(tj * 4 + qj * 2 + 1) * 524288 + koff;
  f32x16 acc00, acc01, acc10, acc11;
#pragma unroll
  for (int i = 0; i < 16; ++i) {
    acc00[i] = 0.f; acc01[i] = 0.f; acc10[i] = 0.f; acc11[i] = 0.f;
  }
#pragma unroll 4
  for (int s = 0; s < 32; ++s) {
    bf16x8 a0 = ldbf16x8(A0 + s * 512);
    bf16x8 a1 = ldbf16x8(A1 + s * 512);
    bf16x8 b0 = ldbf16x8(B0 + s * 512);
    bf16x8 b1 = ldbf16x8(B1 + s * 512);
    acc00 = __builtin_amdgcn_mfma_f32_32x32x16_bf16(a0, b0, acc00, 0, 0, 0);
    acc01 = __builtin_amdgcn_mfma_f32_32x32x16_bf16(a0, b1, acc01, 0, 0, 0);
    acc10 = __builtin_amdgcn_mfma_f32_32x32x16_bf16(a1, b0, acc10, 0, 0, 0);
    acc11 = __builtin_amdgcn_mfma_f32_32x32x16_bf16(a1, b1, acc11, 0, 0, 0);
  }
  float* __restrict__ P = Cpart + (((size_t)g * 4 + tp) * 32 + kc) * 16384;
#pragma unroll
  for (int r = 0; r < 16; ++r) {
    const int rr = (r & 3) + 8 * (r >> 2) + 4 * half;
    const int row0 = qi * 64 + rr, col0 = qj * 64 + lc;
    P[(row0 +  0) * 128 + col0 +  0] = acc00[r];
    P[(row0 +  0) * 128 + col0 + 32] = acc01[r];
    P[(row0 + 32) * 128 + col0 +  0] = acc10[r];
    P[(row0 + 32) * 128 + col0 + 32] = acc11[r];
  }
}

__global__ __launch_bounds__(256)
void k1b_red(const float* __restrict__ Cpart, float* __restrict__ Cmat) {
  const int sl = blockIdx.x;
  const int tp = blockIdx.y;
  const int g  = blockIdx.z;
  const int ele = sl * 256 + threadIdx.x;
  const float* __restrict__ P =
      Cpart + (((size_t)g * 4 + tp) * 32) * 16384 + ele;
  float v = 0.f;
#pragma unroll
  for (int kc = 0; kc < 32; ++kc) v += P[(size_t)kc * 16384];
  const int ti = tp >> 1, tj = tp & 1;
  const int i = ele >> 7, j = ele & 127;
  Cmat[(size_t)g * 65536 + (size_t)(ti * 128 + i) * 256 + tj * 128 + j] = v;
}

__global__ __launch_bounds__(256)
void kA_attn(const float* __restrict__ Wq, const float* __restrict__ Wkv,
             const float* __restrict__ Cmat, float* __restrict__ attn) {
  __shared__ float WqL[4 * 256];
  __shared__ float Ts[4 * 256];
  const int bh = blockIdx.x;
  const int ic = blockIdx.y;
  const int g = bh >> 3, hh = bh & 7;
  const int tid = threadIdx.x;
  const float* __restrict__ Cg = Cmat + (size_t)g * 65536;
  {
    const int r = tid >> 6, c4 = (tid & 63) * 4;
    *(float4*)(&WqL[r * 256 + c4]) =
        *(const float4*)(Wq + (size_t)(hh * 64 + ic * 4 + r) * 256 + c4);
  }
  __syncthreads();
  float acc[4] = {0.f, 0.f, 0.f, 0.f};
#pragma unroll 8
  for (int b = 0; b < 256; ++b) {
    const float cv = Cg[(size_t)b * 256 + tid];
#pragma unroll
    for (int r = 0; r < 4; ++r) acc[r] += WqL[r * 256 + b] * cv;
  }
#pragma unroll
  for (int r = 0; r < 4; ++r) Ts[r * 256 + tid] = acc[r];
  __syncthreads();
  const int r = tid >> 6, j = tid & 63;
  const float* __restrict__ Wk = Wkv + (size_t)(hh * 64 + j) * 256;
  float s = 0.f;
#pragma unroll 4
  for (int a4 = 0; a4 < 64; ++a4) {
    float4 w = *(const float4*)(Wk + a4 * 4);
    const float* t4 = &Ts[r * 256 + a4 * 4];
    s += t4[0] * w.x + t4[1] * w.y + t4[2] * w.z + t4[3] * w.w;
  }
  s *= 0.125f;
  float m = s;
#pragma unroll
  for (int off = 32; off; off >>= 1) m = fmaxf(m, __shfl_xor(m, off));
  const float e = __expf(s - m);
  float sum = e;
#pragma unroll
  for (int off = 32; off; off >>= 1) sum += __shfl_xor(sum, off);
  attn[((size_t)bh * 64 + ic * 4 + r) * 64 + j] = e / sum;
}

__global__ __launch_bounds__(256)
void kB_m(const float* __restrict__ Wout, const float* __restrict__ Wkv,
          const float* __restrict__ attn, float* __restrict__ Mp) {
  __shared__ float AtL[64 * 64];
  __shared__ float WoL[16 * 64];
  __shared__ float UL[16 * 64];
  const int bh = blockIdx.x;
  const int cc = blockIdx.y;
  const int g = bh >> 3, hh = bh & 7;
  const int tid = threadIdx.x;
  {
    const float* __restrict__ A = attn + (size_t)bh * 4096;
#pragma unroll
    for (int q = 0; q < 4; ++q)
      *(float4*)(&AtL[q * 1024 + tid * 4]) =
          *(const float4*)(A + q * 1024 + tid * 4);
  }
  {
    const int co_l = tid >> 4, i4 = (tid & 15) * 4;
    *(float4*)(&WoL[co_l * 64 + i4]) =
        *(const float4*)(Wout + (size_t)(cc * 16 + co_l) * 512 + hh * 64 + i4);
  }
  __syncthreads();
  const int j = tid & 63, cw = tid >> 6;
  float u4[4] = {0.f, 0.f, 0.f, 0.f};
#pragma unroll 4
  for (int i = 0; i < 64; ++i) {
    const float av = AtL[i * 64 + j];
#pragma unroll
    for (int u = 0; u < 4; ++u) u4[u] += WoL[(cw * 4 + u) * 64 + i] * av;
  }
  __syncthreads();
#pragma unroll
  for (int u = 0; u < 4; ++u) UL[(cw * 4 + u) * 64 + j] = u4[u];
  __syncthreads();
  float acc[16];
#pragma unroll
  for (int c = 0; c < 16; ++c) acc[c] = 0.f;
#pragma unroll 4
  for (int j2 = 0; j2 < 64; ++j2) {
    const float wv = Wkv[(size_t)(512 + hh * 64 + j2) * 256 + tid];
#pragma unroll
    for (int c = 0; c < 16; ++c) acc[c] += UL[c * 64 + j2] * wv;
  }
  float* __restrict__ P =
      Mp + (((size_t)g * 8 + hh) * 256 + cc * 16) * 256 + tid;
#pragma unroll
  for (int c = 0; c < 16; ++c) P[(size_t)c * 256] = acc[c];
}

__global__ __launch_bounds__(256)
void kC_red(const float* __restrict__ Mp, u16* __restrict__ MA) {
  const int panel = blockIdx.x >> 2;
  const int q     = blockIdx.x & 3;
  const int g     = blockIdx.y;
  const int tid = threadIdx.x;
  const float* __restrict__ Pg = Mp + (size_t)g * 8 * 65536;
  u16* __restrict__ Mg = MA + (size_t)g * 65536;
  const int item = tid + q * 256;
  const int lc = item & 31;
  const int co = panel * 32 + lc;
  const int b0 = (item >> 5) * 8;
  float v[8] = {0.f, 0.f, 0.f, 0.f, 0.f, 0.f, 0.f, 0.f};
#pragma unroll
  for (int hd = 0; hd < 8; ++hd) {
    const float* p = Pg + (size_t)hd * 65536 + (size_t)co * 256 + b0;
    float4 a = *(const float4*)(p);
    float4 b = *(const float4*)(p + 4);
    v[0] += a.x; v[1] += a.y; v[2] += a.z; v[3] += a.w;
    v[4] += b.x; v[5] += b.y; v[6] += b.z; v[7] += b.w;
  }
  uint4 sdat;
  sdat.x = (u32)f2bf(v[0]) | ((u32)f2bf(v[1]) << 16);
  sdat.y = (u32)f2bf(v[2]) | ((u32)f2bf(v[3]) << 16);
  sdat.z = (u32)f2bf(v[4]) | ((u32)f2bf(v[5]) << 16);
  sdat.w = (u32)f2bf(v[6]) | ((u32)f2bf(v[7]) << 16);
  *(uint4*)(Mg + (size_t)panel * 8192 + (size_t)item * 8) = sdat;
}

__global__ __launch_bounds__(256)
void k6_mfma(const u16* __restrict__ XbTF, const u16* __restrict__ MA,
             const float* __restrict__ bout, float* __restrict__ out) {
  const int pb = blockIdx.x;
  const int cb = blockIdx.y;
  const int g  = blockIdx.z;
  const int tid = threadIdx.x;
  const int w = tid >> 6, half = (tid >> 5) & 1, lc = tid & 31;
  const int p0  = pb * 128 + w * 32;
  const int co0 = cb * 128;
  const u16* __restrict__ Ap = XbTF + (size_t)g * NP * 256 +
                               (size_t)(pb * 4 + w) * 8192 + half * 256 +
                               lc * 8;
  const u16* __restrict__ Bp = MA + (size_t)g * 65536 +
                               (size_t)cb * 32768 + half * 256 + lc * 8;
  f32x16 acc[4];
#pragma unroll
  for (int t = 0; t < 4; ++t)
#pragma unroll
    for (int i = 0; i < 16; ++i) acc[t][i] = 0.f;
#pragma unroll 2
  for (int s = 0; s < 16; ++s) {
    bf16x8 a = ldbf16x8(Ap + s * 512);
#pragma unroll
    for (int t = 0; t < 4; ++t) {
      bf16x8 b = ldbf16x8(Bp + (size_t)t * 8192 + s * 512);
      acc[t] = __builtin_amdgcn_mfma_f32_32x32x16_bf16(a, b, acc[t], 0, 0, 0);
    }
  }
#pragma unroll
  for (int t = 0; t < 4; ++t) {
    const int co = co0 + t * 32 + lc;
    const float bo = bout[co];
    float* __restrict__ ocol =
        out + ((size_t)(g * 256 + co)) * NP + p0 + 4 * half;
#pragma unroll
    for (int rg = 0; rg < 4; ++rg) {
      float4 v = {acc[t][rg * 4 + 0] + bo, acc[t][rg * 4 + 1] + bo,
                  acc[t][rg * 4 + 2] + bo, acc[t][rg * 4 + 3] + bo};
      *(float4*)(ocol + rg * 8) = v;
    }
  }
}

// ---------------------------------------------------------------------------
// Fallback tier 2: fp32 split-K Gram (known-good).
__global__ __launch_bounds__(256)
void k1_gram(const float* __restrict__ x, float* __restrict__ Cpart) {
  __shared__ float As[32 * 132];
  __shared__ float Bs[32 * 132];
  const int kc = blockIdx.x, ty = blockIdx.y, g = blockIdx.z;
  const int i0 = (ty == 2) ? 128 : 0;
  const int j0 = (ty == 0) ? 0 : 128;
  const float* __restrict__ Xg = x + (size_t)g * 256 * NP;
  const int tid = threadIdx.x, lane = tid & 63, w = tid >> 6;
  const int wy = (w >> 1) * 64, wx = (w & 1) * 64;
  const int ly = (lane >> 3) * 8, lx = (lane & 7) * 8;
  float acc[8][8];
#pragma unroll
  for (int e = 0; e < 8; ++e)
#pragma unroll
    for (int f = 0; f < 8; ++f) acc[e][f] = 0.f;
  const int k8 = (tid & 3) * 8, rowb = tid >> 2, k0 = kc * 256;
  for (int s = 0; s < 8; ++s) {
    const int ks = k0 + s * 32;
#pragma unroll
    for (int pass = 0; pass < 2; ++pass) {
      const int row = rowb + pass * 64;
      const size_t ea = (size_t)(i0 + row) * NP + ks + k8;
      float4 a = *(const float4*)(Xg + ea);
      float4 b = *(const float4*)(Xg + ea + 4);
      As[(k8+0)*132+row]=a.x; As[(k8+1)*132+row]=a.y;
      As[(k8+2)*132+row]=a.z; As[(k8+3)*132+row]=a.w;
      As[(k8+4)*132+row]=b.x; As[(k8+5)*132+row]=b.y;
      As[(k8+6)*132+row]=b.z; As[(k8+7)*132+row]=b.w;
      const size_t eb = (size_t)(j0 + row) * NP + ks + k8;
      a = *(const float4*)(Xg + eb);
      b = *(const float4*)(Xg + eb + 4);
      Bs[(k8+0)*132+row]=a.x; Bs[(k8+1)*132+row]=a.y;
      Bs[(k8+2)*132+row]=a.z; Bs[(k8+3)*132+row]=a.w;
      Bs[(k8+4)*132+row]=b.x; Bs[(k8+5)*132+row]=b.y;
      Bs[(k8+6)*132+row]=b.z; Bs[(k8+7)*132+row]=b.w;
    }
    __syncthreads();
#pragma unroll 4
    for (int kk = 0; kk < 32; ++kk) {
      const float* ar = &As[kk * 132 + wy + ly];
      const float* br = &Bs[kk * 132 + wx + lx];
      float4 a0 = *(const float4*)(ar), a1 = *(const float4*)(ar + 4);
      float4 b0 = *(const float4*)(br), b1 = *(const float4*)(br + 4);
      const float av[8] = {a0.x,a0.y,a0.z,a0.w,a1.x,a1.y,a1.z,a1.w};
      const float bv[8] = {b0.x,b0.y,b0.z,b0.w,b1.x,b1.y,b1.z,b1.w};
#pragma unroll
      for (int e = 0; e < 8; ++e)
#pragma unroll
        for (int f = 0; f < 8; ++f) acc[e][f] += av[e] * bv[f];
    }
    __syncthreads();
  }
  float* __restrict__ P = Cpart + (((size_t)g * 3 + ty) * 64 + kc) * 16384;
#pragma unroll
  for (int e = 0; e < 8; ++e) {
    float* pr = P + (size_t)(wy + ly + e) * 128 + wx + lx;
    float4 s0 = {acc[e][0], acc[e][1], acc[e][2], acc[e][3]};
    float4 s1 = {acc[e][4], acc[e][5], acc[e][6], acc[e][7]};
    *(float4*)(pr)     = s0;
    *(float4*)(pr + 4) = s1;
  }
}

__global__ __launch_bounds__(256)
void k1b_reduce(const float* __restrict__ Cpart, float* __restrict__ Cmat) {
  const int sl = blockIdx.x, ty = blockIdx.y, g = blockIdx.z;
  const int ele = sl * 256 + threadIdx.x;
  const float* __restrict__ P =
      Cpart + (((size_t)g * 3 + ty) * 64) * 16384 + ele;
  float v = 0.f;
#pragma unroll 8
  for (int kc = 0; kc < 64; ++kc) v += P[(size_t)kc * 16384];
  const int i0 = (ty == 2) ? 128 : 0;
  const int j0 = (ty == 0) ? 0 : 128;
  const int i = ele >> 7, j = ele & 127;
  float* Cg = Cmat + (size_t)g * 65536;
  Cg[(size_t)(i0 + i) * 256 + (j0 + j)] = v;
  if (ty == 1) Cg[(size_t)(j0 + j) * 256 + (i0 + i)] = v;
}

// Fallback tier 3 (tiny ws): atomic Gram.
__global__ __launch_bounds__(256)
void k1_gram_atomic(const float* __restrict__ x, float* __restrict__ Cmat) {
  __shared__ float As[32 * 132];
  __shared__ float Bs[32 * 132];
  const int kc = blockIdx.x, ty = blockIdx.y, g = blockIdx.z;
  const int i0 = (ty == 2) ? 128 : 0;
  const int j0 = (ty == 0) ? 0 : 128;
  const float* __restrict__ Xg = x + (size_t)g * 256 * NP;
  const int tid = threadIdx.x, lane = tid & 63, w = tid >> 6;
  const int wy = (w >> 1) * 64, wx = (w & 1) * 64;
  const int ly = (lane >> 3) * 8, lx = (lane & 7) * 8;
  float acc[8][8];
#pragma unroll
  for (int e = 0; e < 8; ++e)
#pragma unroll
    for (int f = 0; f < 8; ++f) acc[e][f] = 0.f;
  const int k8 = (tid & 3) * 8, rowb = tid >> 2, k0 = kc * 256;
  for (int s = 0; s < 8; ++s) {
    const int ks = k0 + s * 32;
#pragma unroll
    for (int pass = 0; pass < 2; ++pass) {
      const int row = rowb + pass * 64;
      const size_t ea = (size_t)(i0 + row) * NP + ks + k8;
      float4 a = *(const float4*)(Xg + ea);
      float4 b = *(const float4*)(Xg + ea + 4);
      As[(k8+0)*132+row]=a.x; As[(k8+1)*132+row]=a.y;
      As[(k8+2)*132+row]=a.z; As[(k8+3)*132+row]=a.w;
      As[(k8+4)*132+row]=b.x; As[(k8+5)*132+row]=b.y;
      As[(k8+6)*132+row]=b.z; As[(k8+7)*132+row]=b.w;
      const size_t eb = (size_t)(j0 + row) * NP + ks + k8;
      a = *(const float4*)(Xg + eb);
      b = *(const float4*)(Xg + eb + 4);
      Bs[(k8+0)*132+row]=a.x; Bs[(k8+1)*132+row]=a.y;
      Bs[(k8+2)*132+row]=a.z; Bs[(k8+3)*132+row]=a.w;
      Bs[(k8+4)*132+row]=b.x; Bs[(k8+5)*132+row]=b.y;
      Bs[(k8+6)*132+row]=b.z; Bs[(k8+7)*132+row]=b.w;
    }
    __syncthreads();
#pragma unroll 4
    for (int kk = 0; kk < 32; ++kk) {
      const float* ar = &As[kk * 132 + wy + ly];
      const float* br = &Bs[kk * 132 + wx + lx];
      float4 a0 = *(const float4*)(ar), a1 = *(const float4*)(ar + 4);
      float4 b0 = *(const float4*)(br), b1 = *(const float4*)(br + 4);
      const float av[8] = {a0.x,a0.y,a0.z,a0.w,a1.x,a1.y,a1.z,a1.w};
      const float bv[8] = {b0.x,b0.y,b0.z,b0.w,b1.x,b1.y,b1.z,b1.w};
#pragma unroll
      for (int e = 0; e < 8; ++e)
#pragma unroll
        for (int f = 0; f < 8; ++f) acc[e][f] += av[e] * bv[f];
    }
    __syncthreads();
  }
  float* Cg = Cmat + (size_t)g * 65536;
#pragma unroll
  for (int e = 0; e < 8; ++e)
#pragma unroll
    for (int f = 0; f < 8; ++f) {
      atomicAdd(&Cg[(i0+wy+ly+e)*256 + (j0+wx+lx+f)], acc[e][f]);
      if (ty == 1)
        atomicAdd(&Cg[(j0+wx+lx+f)*256 + (i0+wy+ly+e)], acc[e][f]);
    }
}

// ---------------------------------------------------------------------------
// Fallback middle chain (tiers 2/3).
__global__ __launch_bounds__(256) void k2_T(const float* __restrict__ Wq,
                                            const float* __restrict__ Cmat,
                                            float* __restrict__ T) {
  const int bh = blockIdx.x;
  const int ic = blockIdx.y;
  const int g = bh >> 3, hh = bh & 7;
  const int tid = threadIdx.x;
  const float* __restrict__ Cg = Cmat + (size_t)g * 65536;
  const int r0 = hh * 64 + ic * 4;
  float acc[4] = {0.f, 0.f, 0.f, 0.f};
#pragma unroll 8
  for (int b = 0; b < 256; ++b) {
    const float cv = Cg[(size_t)b * 256 + tid];
#pragma unroll
    for (int ii = 0; ii < 4; ++ii)
      acc[ii] += Wq[(size_t)(r0 + ii) * 256 + b] * cv;
  }
#pragma unroll
  for (int ii = 0; ii < 4; ++ii)
    T[((size_t)bh * 64 + ic * 4 + ii) * 256 + tid] = acc[ii];
}

__global__ __launch_bounds__(256) void k3_sim(const float* __restrict__ Wkv,
                                              const float* __restrict__ T,
                                              float* __restrict__ simattn) {
  __shared__ float Ts[64 * 256];
  const int bh = blockIdx.x;
  const int jc = blockIdx.y;
  const int hh = bh & 7;
  const int tid = threadIdx.x;
  {
    const int f4i = tid & 63;
    const int rwb = tid >> 6;
    for (int pass = 0; pass < 16; ++pass) {
      const int row = rwb + pass * 4;
      float4 v = *(const float4*)(T + ((size_t)bh * 64 + row) * 256 + f4i * 4);
      const int a0 = f4i * 4;
      const float vv[4] = {v.x, v.y, v.z, v.w};
#pragma unroll
      for (int e = 0; e < 4; ++e) {
        const int a = a0 + e;
        Ts[row * 256 + (a & ~31) + ((a + row) & 31)] = vv[e];
      }
    }
  }
  __syncthreads();
  const int i  = tid & 63;
  const int jq = tid >> 6;
  const int jb = jc * 16 + jq * 4;
  float acc[4] = {0.f, 0.f, 0.f, 0.f};
#pragma unroll 4
  for (int a = 0; a < 256; ++a) {
    const float tv = Ts[i * 256 + (a & ~31) + ((a + i) & 31)];
#pragma unroll
    for (int jj = 0; jj < 4; ++jj)
      acc[jj] += Wkv[(size_t)(hh * 64 + jb + jj) * 256 + a] * tv;
  }
#pragma unroll
  for (int jj = 0; jj < 4; ++jj)
    simattn[((size_t)bh * 64 + i) * 64 + jb + jj] = acc[jj] * 0.125f;
}

__global__ __launch_bounds__(64) void k3b_softmax(float* __restrict__ simattn) {
  const int bh = blockIdx.x;
  const int i  = threadIdx.x;
  float* row = simattn + ((size_t)bh * 64 + i) * 64;
  float v[64];
  float m = -1e30f;
#pragma unroll
  for (int j = 0; j < 64; ++j) { v[j] = row[j]; m = fmaxf(m, v[j]); }
  float s = 0.f;
#pragma unroll
  for (int j = 0; j < 64; ++j) { v[j] = __expf(v[j] - m); s += v[j]; }
  const float inv = 1.0f / s;
#pragma unroll
  for (int j = 0; j < 64; ++j) row[j] = v[j] * inv;
}

__global__ __launch_bounds__(256) void k4_we(const float* __restrict__ Wout,
                                             const float* __restrict__ attn,
                                             float* __restrict__ WeT) {
  __shared__ float WL[256 * 64];
  const int jc = blockIdx.x;
  const int hh = blockIdx.y;
  const int g  = blockIdx.z;
  const int bh = g * 8 + hh;
  const int tid = threadIdx.x;
  {
    const int f4i = tid & 15;
    const int cb  = tid >> 4;
    for (int pass = 0; pass < 16; ++pass) {
      const int co = cb + pass * 16;
      float4 v = *(const float4*)(Wout + (size_t)co * 512 + hh * 64 + f4i * 4);
      const int a0 = f4i * 4;
      const float vv[4] = {v.x, v.y, v.z, v.w};
#pragma unroll
      for (int e = 0; e < 4; ++e)
        WL[co * 64 + ((a0 + e + co) & 63)] = vv[e];
    }
  }
  __syncthreads();
  const int jb = jc * 8;
  float acc[8] = {0.f, 0.f, 0.f, 0.f, 0.f, 0.f, 0.f, 0.f};
#pragma unroll 4
  for (int i = 0; i < 64; ++i) {
    const float wv = WL[tid * 64 + ((i + tid) & 63)];
#pragma unroll
    for (int je = 0; je < 8; ++je)
      acc[je] += attn[((size_t)bh * 64 + i) * 64 + jb + je] * wv;
  }
#pragma unroll
  for (int je = 0; je < 8; ++je)
    WeT[(size_t)g * 131072 + (size_t)(hh * 64 + jb + je) * 256 + tid] =
        acc[je];
}

__global__ __launch_bounds__(256)
void k5a_part(const float* __restrict__ Wkv, const float* __restrict__ WeT,
              float* __restrict__ Mp) {
  const int bc = blockIdx.x;
  const int oc = blockIdx.y;
  const int g  = blockIdx.z;
  const int tid = threadIdx.x;
  const int b0 = bc * 4;
  const float* __restrict__ Weg = WeT + (size_t)g * 131072;
  float acc[4] = {0.f, 0.f, 0.f, 0.f};
#pragma unroll 8
  for (int u = 0; u < 32; ++u) {
    const int o = oc * 32 + u;
    const float wv = Weg[(size_t)o * 256 + tid];
    const float* __restrict__ vr = Wkv + (size_t)(512 + o) * 256 + b0;
    acc[0] += vr[0] * wv;
    acc[1] += vr[1] * wv;
    acc[2] += vr[2] * wv;
    acc[3] += vr[3] * wv;
  }
#pragma unroll
  for (int be = 0; be < 4; ++be)
    Mp[(((size_t)g * 16 + oc) * 256 + b0 + be) * 256 + tid] = acc[be];
}

__global__ __launch_bounds__(256)
void k5b_red(const float* __restrict__ Mp, float* __restrict__ Mt,
             u16* __restrict__ MA) {
  const int b = blockIdx.x;
  const int g = blockIdx.y;
  const int tid = threadIdx.x;
  const float* __restrict__ P =
      Mp + ((size_t)g * 16 * 256 + b) * 256 + tid;
  float v = 0.f;
#pragma unroll
  for (int oc = 0; oc < 16; ++oc) v += P[(size_t)oc * 65536];
  Mt[(size_t)g * 65536 + (size_t)b * 256 + tid] = v;
  MA[(size_t)g * 65536 + (size_t)tid * 256 + b] = f2bf(v);
}

__global__ __launch_bounds__(256) void k5_serial(const float* __restrict__ Wkv,
                                                 const float* __restrict__ WeT,
                                                 float* __restrict__ Mt,
                                                 u16* __restrict__ MA) {
  const int bc = blockIdx.x;
  const int g  = blockIdx.y;
  const int tid = threadIdx.x;
  const int b0 = bc * 4;
  const float* __restrict__ Weg = WeT + (size_t)g * 131072;
  float acc[4] = {0.f, 0.f, 0.f, 0.f};
#pragma unroll 4
  for (int o = 0; o < 512; ++o) {
    const float wv = Weg[(size_t)o * 256 + tid];
    const float* __restrict__ vr = Wkv + (size_t)(512 + o) * 256 + b0;
    acc[0] += vr[0] * wv;
    acc[1] += vr[1] * wv;
    acc[2] += vr[2] * wv;
    acc[3] += vr[3] * wv;
  }
#pragma unroll
  for (int be = 0; be < 4; ++be) {
    Mt[(size_t)g * 65536 + (size_t)(b0 + be) * 256 + tid] = acc[be];
    MA[(size_t)g * 65536 + (size_t)tid * 256 + b0 + be] = f2bf(acc[be]);
  }
}

// Fallback fp32 K6.
__global__ __launch_bounds__(256)
void k6_apply(const float* __restrict__ x, const float* __restrict__ Mt,
              const float* __restrict__ bout, float* __restrict__ out) {
  __shared__ float As[32 * 132];
  __shared__ float Bs[32 * 132];
  const int pc = blockIdx.x;
  const int oy = blockIdx.y;
  const int g  = blockIdx.z;
  const int p0 = pc * 128;
  const int o0 = oy * 128;
  const float* __restrict__ Xg = x + (size_t)g * 256 * NP;
  const float* __restrict__ Mg = Mt + (size_t)g * 65536;
  const int tid  = threadIdx.x;
  const int lane = tid & 63;
  const int w    = tid >> 6;
  const int wy = (w >> 1) * 64;
  const int wx = (w & 1) * 64;
  const int ly = (lane >> 3) * 8;
  const int lx = (lane & 7) * 8;
  float acc[8][8];
#pragma unroll
  for (int e = 0; e < 8; ++e)
#pragma unroll
    for (int f = 0; f < 8; ++f) acc[e][f] = 0.f;
  const int c4 = (tid & 31) * 4;
  const int kb = tid >> 5;
  for (int s = 0; s < 8; ++s) {
#pragma unroll
    for (int r = 0; r < 4; ++r) {
      const int kk = kb + r * 8;
      const int f  = s * 32 + kk;
      *(float4*)&As[kk * 132 + c4] =
          *(const float4*)(Mg + (size_t)f * 256 + o0 + c4);
      *(float4*)&Bs[kk * 132 + c4] =
          *(const float4*)(Xg + (size_t)f * NP + p0 + c4);
    }
    __syncthreads();
#pragma unroll 4
    for (int kk = 0; kk < 32; ++kk) {
      const float* __restrict__ ar = &As[kk * 132 + wy + ly];
      const float* __restrict__ br = &Bs[kk * 132 + wx + lx];
      float4 a0 = *(const float4*)(ar);
      float4 a1 = *(const float4*)(ar + 4);
      float4 b0 = *(const float4*)(br);
      float4 b1 = *(const float4*)(br + 4);
      const float av[8] = {a0.x, a0.y, a0.z, a0.w, a1.x, a1.y, a1.z, a1.w};
      const float bv[8] = {b0.x, b0.y, b0.z, b0.w, b1.x, b1.y, b1.z, b1.w};
#pragma unroll
      for (int e = 0; e < 8; ++e)
#pragma unroll
        for (int f = 0; f < 8; ++f) acc[e][f] += av[e] * bv[f];
    }
    __syncthreads();
  }
#pragma unroll
  for (int e = 0; e < 8; ++e) {
    const int co = o0 + wy + ly + e;
    const float bo = bout[co];
    float* __restrict__ orow =
        out + ((size_t)(g * 256 + co)) * NP + p0 + wx + lx;
    float4 s0 = {acc[e][0] + bo, acc[e][1] + bo, acc[e][2] + bo,
                 acc[e][3] + bo};
    float4 s1 = {acc[e][4] + bo, acc[e][5] + bo, acc[e][6] + bo,
                 acc[e][7] + bo};
    *(float4*)(orow)     = s0;
    *(float4*)(orow + 4) = s1;
  }
}

// ---------------------------------------------------------------------------
extern "C" void kernel_launch(void* const* d_in, const int* in_sizes, int n_in,
                              void* d_out, int out_size, void* d_ws,
                              size_t ws_size, hipStream_t stream) {
  const float* x    = (const float*)d_in[0];
  const float* Wq   = (const float*)d_in[1];
  const float* Wkv  = (const float*)d_in[2];
  const float* Wout = (const float*)d_in[3];
  const float* bout = (const float*)d_in[4];
  float* out = (float*)d_out;
  float* ws  = (float*)d_ws;

  float* C    = ws + OFF_C;
  float* T    = ws + OFF_T;
  float* att  = ws + OFF_AT;
  float* WeT  = ws + OFF_WE;
  float* Mt   = ws + OFF_MT;
  u16*   MA   = (u16*)(ws + OFF_MA);
  u16*   Xb   = (u16*)(ws + OFF_XB);
  u16*   XbT  = (u16*)(ws + OFF_XBT);
  float* Cp1  = ws + OFF_CP1;
  float* Cp2  = ws + OFF_CP2;

  const bool mfma_path = (ws_size >= NEED1);
  const bool splitk    = (ws_size >= NEED2);

  if (mfma_path) {
    // Try single cooperative kernel (grid.sync between phases).  Co-residency
    // is validated by the runtime; on ANY launch error fall back to the
    // known-good 7-kernel chain.
    void* args[] = {(void*)&x,   (void*)&Wq,  (void*)&Wkv, (void*)&Wout,
                    (void*)&bout,(void*)&out, (void*)&Xb,  (void*)&XbT,
                    (void*)&C,   (void*)&att, (void*)&MA,  (void*)&Cp1};
    hipError_t err = hipLaunchCooperativeKernel(
        (const void*)fused_all, dim3(512), dim3(256), args, 0, stream);
    if (err == hipSuccess) return;
    (void)hipGetLastError();  // clear sticky error, use fallback chain
    k0_cvt<<<dim3(256, 2), 256, 0, stream>>>(x, Xb, XbT);
    k1_mfma<<<dim3(4, 32, 2), 256, 0, stream>>>(Xb, Cp1);
    k1b_red<<<dim3(64, 4, 2), 256, 0, stream>>>(Cp1, C);
    kA_attn<<<dim3(16, 16), 256, 0, stream>>>(Wq, Wkv, C, att);
    kB_m<<<dim3(16, 16), 256, 0, stream>>>(Wout, Wkv, att, Cp1);
    kC_red<<<dim3(32, 2), 256, 0, stream>>>(Cp1, MA);
    k6_mfma<<<dim3(128, 2, 2), 256, 0, stream>>>(XbT, MA, bout, out);
    return;
  }

  // Fallback tiers (original chain).
  if (splitk) {
    k1_gram<<<dim3(64, 3, 2), 256, 0, stream>>>(x, Cp2);
    k1b_reduce<<<dim3(64, 3, 2), 256, 0, stream>>>(Cp2, C);
  } else {
    hipMemsetAsync(C, 0, 131072 * sizeof(float), stream);
    k1_gram_atomic<<<dim3(64, 3, 2), 256, 0, stream>>>(x, C);
  }
  k2_T<<<dim3(16, 16), 256, 0, stream>>>(Wq, C, T);
  k3_sim<<<dim3(16, 4), 256, 0, stream>>>(Wkv, T, att);
  k3b_softmax<<<dim3(16), 64, 0, stream>>>(att);
  k4_we<<<dim3(8, 8, 2), 256, 0, stream>>>(Wout, att, WeT);
  if (splitk) {
    k5a_part<<<dim3(64, 16, 2), 256, 0, stream>>>(Wkv, WeT, Cp2);
    k5b_red<<<dim3(256, 2), 256, 0, stream>>>(Cp2, Mt, MA);
  } else {
    k5_serial<<<dim3(64, 2), 256, 0, stream>>>(Wkv, WeT, Mt, MA);
  }
  k6_apply<<<dim3(128, 2, 2), 256, 0, stream>>>(x, Mt, bout, out);
}

// Round 7
// 194.447 us; speedup vs baseline: 2.5282x; 2.5282x over previous
//
#include <hip/hip_runtime.h>
#include <cstdint>
#include <cstddef>

using u16 = unsigned short;
using u32 = unsigned int;

typedef __attribute__((ext_vector_type(8))) short bf16x8;   // 8 bf16 = 4 VGPRs
typedef __attribute__((ext_vector_type(16))) float f32x16;  // MFMA 32x32 acc

__device__ __forceinline__ u16 f2bf(float f) {  // round-to-nearest-even
  union { float f; u32 i; } x; x.f = f;
  u32 r = (x.i + 0x7FFFu + ((x.i >> 16) & 1u)) >> 16;
  return (u16)r;
}
__device__ __forceinline__ bf16x8 ldbf16x8(const u16* p) {
  union { uint4 u; bf16x8 v; } t;
  t.u = *(const uint4*)p;
  return t.v;
}

// Geometry: x (16,32,128,128) fp32 -> G=2 groups, F=256 features/group,
// N=16384 positions, 8 heads/group, dim_head=64.  Collapse:
// C[g]=F·F^T Gram; sim=Wq_h·C·Wk_h^T; attn=softmax; M=(Wout·bd(attn))·Wv;
// out = M·f + bout.
constexpr int NP = 16384;

// Fragment-tiled bf16 layouts: element (row, k) lives at
//   [panel=row>>5][s=k>>4][h=(k>>3)&1][lc=row&31][j=k&7]
// XbF  : rows=256 f,  k=16384 p   -> panel stride 524288 (u16 units)
// MAF  : rows=256 co, k=256 f(=b) -> panel stride 8192
// (XbT eliminated in R7: k6 transposes XbF tiles in LDS.)

// ws layout (fp32 element offsets)
constexpr size_t OFF_C   = 0;        // C[2][256][256]        131072
constexpr size_t OFF_T   = 131072;   // T (fallback)          262144
constexpr size_t OFF_AT  = 393216;   // sim/attn[16][64][64]   65536
constexpr size_t OFF_WE  = 458752;   // WeT (fallback)        262144
constexpr size_t OFF_MT  = 720896;   // Mt (fallback)         131072
constexpr size_t OFF_MA  = 851968;   // MAF bf16 [2][...]     (65536 fl)
constexpr size_t OFF_XB  = 917504;   // XbF  bf16 [2][...]    (4194304 fl)
constexpr size_t OFF_CP1 = 5111808;  // Cpart1 [2][4tp][32kc][16384] (4194304)
constexpr size_t NEED1   = (OFF_CP1 + 4194304) * 4;  // 37,224,448 B
constexpr size_t OFF_CP2 = 851968;   // fp32-fallback partials (6291456 fl)
constexpr size_t NEED2   = (OFF_CP2 + 6291456) * 4;  // 28,573,696 B

// ---------------------------------------------------------------------------
// K0 (R7): x fp32 -> XbF only.  Pure streaming convert, no LDS.
__global__ __launch_bounds__(256)
void k0_cvt(const float* __restrict__ x, u16* __restrict__ XbF) {
  const int pc = blockIdx.x;   // 256 chunks of 64 positions
  const int g  = blockIdx.y;
  const int p0 = pc * 64;
  const float* __restrict__ Xg = x + (size_t)g * 256 * NP;
  u16* __restrict__ XbFg = XbF + (size_t)g * 256 * NP;
  const int tid = threadIdx.x;
  const int f8i = tid & 7, rb = tid >> 3;
  const int sA = pc * 4 + (f8i >> 1);   // k-step (p>>4)
  const int hA = f8i & 1;               // (p>>3)&1
#pragma unroll
  for (int pass = 0; pass < 8; ++pass) {
    const int row = rb + pass * 32;
    const size_t e0 = (size_t)row * NP + p0 + f8i * 8;
    float4 a = *(const float4*)(Xg + e0);
    float4 b = *(const float4*)(Xg + e0 + 4);
    uint4 s;
    s.x = (u32)f2bf(a.x) | ((u32)f2bf(a.y) << 16);
    s.y = (u32)f2bf(a.z) | ((u32)f2bf(a.w) << 16);
    s.z = (u32)f2bf(b.x) | ((u32)f2bf(b.y) << 16);
    s.w = (u32)f2bf(b.z) | ((u32)f2bf(b.w) << 16);
    const int panel = row >> 5, lc = row & 31;
    *(uint4*)(XbFg + (size_t)panel * 524288 + sA * 512 + hA * 256 + lc * 8) = s;
  }
}

// ---------------------------------------------------------------------------
// K1 (MFMA): 128x128 output tiles (2x2 grid); 4 loads feed 4 MFMAs.
__global__ __launch_bounds__(256)
void k1_mfma(const u16* __restrict__ XbF, float* __restrict__ Cpart) {
  const int tp = blockIdx.x;   // 4 tile positions (2x2 of 128x128)
  const int kc = blockIdx.y;   // 32 chunks of 512 positions
  const int g  = blockIdx.z;
  const int ti = tp >> 1, tj = tp & 1;
  const int tid = threadIdx.x;
  const int w = tid >> 6, half = (tid >> 5) & 1, lc = tid & 31;
  const int qi = w >> 1, qj = w & 1;    // 64x64 quadrant per wave
  const u16* __restrict__ Xg = XbF + (size_t)g * 256 * NP;
  const size_t koff = (size_t)kc * 16384 + half * 256 + lc * 8;
  const u16* A0 = Xg + (size_t)(ti * 4 + qi * 2 + 0) * 524288 + koff;
  const u16* A1 = Xg + (size_t)(ti * 4 + qi * 2 + 1) * 524288 + koff;
  const u16* B0 = Xg + (size_t)(tj * 4 + qj * 2 + 0) * 524288 + koff;
  const u16* B1 = Xg + (size_t)(tj * 4 + qj * 2 + 1) * 524288 + koff;
  f32x16 acc00, acc01, acc10, acc11;
#pragma unroll
  for (int i = 0; i < 16; ++i) {
    acc00[i] = 0.f; acc01[i] = 0.f; acc10[i] = 0.f; acc11[i] = 0.f;
  }
#pragma unroll 4
  for (int s = 0; s < 32; ++s) {
    bf16x8 a0 = ldbf16x8(A0 + s * 512);
    bf16x8 a1 = ldbf16x8(A1 + s * 512);
    bf16x8 b0 = ldbf16x8(B0 + s * 512);
    bf16x8 b1 = ldbf16x8(B1 + s * 512);
    acc00 = __builtin_amdgcn_mfma_f32_32x32x16_bf16(a0, b0, acc00, 0, 0, 0);
    acc01 = __builtin_amdgcn_mfma_f32_32x32x16_bf16(a0, b1, acc01, 0, 0, 0);
    acc10 = __builtin_amdgcn_mfma_f32_32x32x16_bf16(a1, b0, acc10, 0, 0, 0);
    acc11 = __builtin_amdgcn_mfma_f32_32x32x16_bf16(a1, b1, acc11, 0, 0, 0);
  }
  float* __restrict__ P = Cpart + (((size_t)g * 4 + tp) * 32 + kc) * 16384;
#pragma unroll
  for (int r = 0; r < 16; ++r) {
    const int rr = (r & 3) + 8 * (r >> 2) + 4 * half;
    const int row0 = qi * 64 + rr, col0 = qj * 64 + lc;
    P[(row0 +  0) * 128 + col0 +  0] = acc00[r];
    P[(row0 +  0) * 128 + col0 + 32] = acc01[r];
    P[(row0 + 32) * 128 + col0 +  0] = acc10[r];
    P[(row0 + 32) * 128 + col0 + 32] = acc11[r];
  }
}

// K1b: sum 32 K-chunk partials per 128x128 tile -> C.
__global__ __launch_bounds__(256)
void k1b_red(const float* __restrict__ Cpart, float* __restrict__ Cmat) {
  const int sl = blockIdx.x;   // 64 slices of 256
  const int tp = blockIdx.y;   // 4
  const int g  = blockIdx.z;
  const int ele = sl * 256 + threadIdx.x;
  const float* __restrict__ P =
      Cpart + (((size_t)g * 4 + tp) * 32) * 16384 + ele;
  float v = 0.f;
#pragma unroll
  for (int kc = 0; kc < 32; ++kc) v += P[(size_t)kc * 16384];
  const int ti = tp >> 1, tj = tp & 1;
  const int i = ele >> 7, j = ele & 127;
  Cmat[(size_t)g * 65536 + (size_t)(ti * 128 + i) * 256 + tj * 128 + j] = v;
}

// ---------------------------------------------------------------------------
// kA (fused k2+k3+k3b): per (bh, ic=4-row chunk): T rows -> sim -> softmax.
__global__ __launch_bounds__(256)
void kA_attn(const float* __restrict__ Wq, const float* __restrict__ Wkv,
             const float* __restrict__ Cmat, float* __restrict__ attn) {
  __shared__ float WqL[4 * 256];
  __shared__ float Ts[4 * 256];
  const int bh = blockIdx.x;   // 16
  const int ic = blockIdx.y;   // 16 chunks of 4 i-rows
  const int g = bh >> 3, hh = bh & 7;
  const int tid = threadIdx.x;
  const float* __restrict__ Cg = Cmat + (size_t)g * 65536;
  {
    const int r = tid >> 6, c4 = (tid & 63) * 4;
    *(float4*)(&WqL[r * 256 + c4]) =
        *(const float4*)(Wq + (size_t)(hh * 64 + ic * 4 + r) * 256 + c4);
  }
  __syncthreads();
  float acc[4] = {0.f, 0.f, 0.f, 0.f};
#pragma unroll 8
  for (int b = 0; b < 256; ++b) {
    const float cv = Cg[(size_t)b * 256 + tid];
#pragma unroll
    for (int r = 0; r < 4; ++r) acc[r] += WqL[r * 256 + b] * cv;
  }
#pragma unroll
  for (int r = 0; r < 4; ++r) Ts[r * 256 + tid] = acc[r];
  __syncthreads();
  const int r = tid >> 6, j = tid & 63;
  const float* __restrict__ Wk = Wkv + (size_t)(hh * 64 + j) * 256;
  float s = 0.f;
#pragma unroll 4
  for (int a4 = 0; a4 < 64; ++a4) {
    float4 w = *(const float4*)(Wk + a4 * 4);
    const float* t4 = &Ts[r * 256 + a4 * 4];
    s += t4[0] * w.x + t4[1] * w.y + t4[2] * w.z + t4[3] * w.w;
  }
  s *= 0.125f;
  float m = s;
#pragma unroll
  for (int off = 32; off; off >>= 1) m = fmaxf(m, __shfl_xor(m, off));
  const float e = __expf(s - m);
  float sum = e;
#pragma unroll
  for (int off = 32; off; off >>= 1) sum += __shfl_xor(sum, off);
  attn[((size_t)bh * 64 + ic * 4 + r) * 64 + j] = e / sum;
}

// ---------------------------------------------------------------------------
// kBC (R7, fused kB+kC): per (cc=8-co chunk, g), loop all 8 heads:
//   U_h[co][j] = sum_i Wout[co][hh*64+i]*attn[bh][i][j];
//   acc[co][b] += sum_j U_h[co][j]*Wv[hh*64+j][b];
// then emit MAF bf16 fragments directly (LDS reshuffle).  No Mp, no kC.
__global__ __launch_bounds__(256)
void kBC_m(const float* __restrict__ Wout, const float* __restrict__ Wkv,
           const float* __restrict__ attn, u16* __restrict__ MA) {
  __shared__ float AtL[64 * 64];   // attn[i][j]
  __shared__ float WoL[8 * 64];    // Wout[co_l][i]
  __shared__ float UL[8 * 64];     // U[co_l][j]
  __shared__ float ML[8 * 257];    // M chunk for writer reshuffle
  const int cc = blockIdx.x;  // 32 chunks of 8 co
  const int g  = blockIdx.y;
  const int tid = threadIdx.x;
  const int j = tid & 63, cw = tid >> 6;
  float acc[8];
#pragma unroll
  for (int c = 0; c < 8; ++c) acc[c] = 0.f;
  for (int hh = 0; hh < 8; ++hh) {
    const int bh = g * 8 + hh;
    {  // stage attn (coalesced float4)
      const float* __restrict__ A = attn + (size_t)bh * 4096;
#pragma unroll
      for (int q = 0; q < 4; ++q)
        *(float4*)(&AtL[q * 1024 + tid * 4]) =
            *(const float4*)(A + q * 1024 + tid * 4);
    }
    if (tid < 128) {  // stage Wout chunk: rows cc*8..+8, cols hh*64..+64
      const int co_l = tid >> 4, i4 = (tid & 15) * 4;
      *(float4*)(&WoL[co_l * 64 + i4]) = *(const float4*)(
          Wout + (size_t)(cc * 8 + co_l) * 512 + hh * 64 + i4);
    }
    __syncthreads();
    // phase 1: U[cw*2+u][j]
    float u2[2] = {0.f, 0.f};
#pragma unroll 4
    for (int i = 0; i < 64; ++i) {
      const float av = AtL[i * 64 + j];
      u2[0] += WoL[(cw * 2 + 0) * 64 + i] * av;
      u2[1] += WoL[(cw * 2 + 1) * 64 + i] * av;
    }
    __syncthreads();
    UL[(cw * 2 + 0) * 64 + j] = u2[0];
    UL[(cw * 2 + 1) * 64 + j] = u2[1];
    __syncthreads();
    // phase 2: thread = b; accumulate 8 co
#pragma unroll 4
    for (int j2 = 0; j2 < 64; ++j2) {
      const float wv = Wkv[(size_t)(512 + hh * 64 + j2) * 256 + tid];
#pragma unroll
      for (int c = 0; c < 8; ++c) acc[c] += UL[c * 64 + j2] * wv;
    }
    __syncthreads();
  }
  // writer reshuffle -> MAF fragments
#pragma unroll
  for (int c = 0; c < 8; ++c) ML[c * 257 + tid] = acc[c];
  __syncthreads();
  u16* __restrict__ Mg = MA + (size_t)g * 65536;
  const int co_l = tid >> 5;          // 0..7
  const int ib   = tid & 31;          // 0..31 -> b0 = ib*8
  const int b0 = ib * 8;
  const int s = b0 >> 4, h = (b0 >> 3) & 1;
  const int co = cc * 8 + co_l;
  const int panel = co >> 5, lc = co & 31;
  const float* mr = &ML[co_l * 257 + b0];
  uint4 sdat;
  sdat.x = (u32)f2bf(mr[0]) | ((u32)f2bf(mr[1]) << 16);
  sdat.y = (u32)f2bf(mr[2]) | ((u32)f2bf(mr[3]) << 16);
  sdat.z = (u32)f2bf(mr[4]) | ((u32)f2bf(mr[5]) << 16);
  sdat.w = (u32)f2bf(mr[6]) | ((u32)f2bf(mr[7]) << 16);
  *(uint4*)(Mg + (size_t)panel * 8192 + s * 512 + h * 256 + lc * 8) = sdat;
}

// ---------------------------------------------------------------------------
// K6 (R7): out[co][p] = sum_f Xb[f][p]*M[co][f] + bout[co].
// A-tile (128p x 256f) staged from XbF into LDS with transpose (once per
// block); fragments then read as clean ds_read_b128.  B = MAF (global).
// LDS 67.6 KB -> 2 blocks/CU, matching the 512-block grid exactly.
__global__ __launch_bounds__(256)
void k6_mfma(const u16* __restrict__ XbF, const u16* __restrict__ MA,
             const float* __restrict__ bout, float* __restrict__ out) {
  __shared__ u16 T[128 * 264];   // [p_local][f], stride 264 u16 (16B-aligned)
  const int pb = blockIdx.x;   // 128 p-blocks of 128
  const int cb = blockIdx.y;   // 2 co-blocks of 128
  const int g  = blockIdx.z;
  const int tid = threadIdx.x;
  const u16* __restrict__ Xg = XbF + (size_t)g * 256 * NP;
  // stage + transpose: 4096 uint4s, 16 per thread; contiguous 8 KB runs/panel
  for (int it = 0; it < 16; ++it) {
    const int idx = it * 256 + tid;              // uint4 index
    const int pa  = idx >> 9;                    // panel (f>>5)
    const int o2  = (idx & 511) * 8;             // u16 offset within slab
    union { uint4 u; u16 e[8]; } v;
    v.u = *(const uint4*)(Xg + (size_t)pa * 524288 + (size_t)pb * 4096 + o2);
    const int sp_l = o2 >> 9;
    const int r    = o2 & 511;
    const int h    = r >> 8;
    const int lcf  = (r >> 3) & 31;
    const int f    = pa * 32 + lcf;
    const int pl   = sp_l * 16 + h * 8;          // p_local base (8 consec)
#pragma unroll
    for (int jj = 0; jj < 8; ++jj) T[(pl + jj) * 264 + f] = v.e[jj];
  }
  __syncthreads();
  const int w = tid >> 6, half = (tid >> 5) & 1, lc = tid & 31;
  const int p0  = pb * 128 + w * 32;
  const int co0 = cb * 128;
  const u16* __restrict__ Ap = &T[(w * 32 + lc) * 264 + half * 8];
  const u16* __restrict__ Bp = MA + (size_t)g * 65536 +
                               (size_t)cb * 32768 + half * 256 + lc * 8;
  f32x16 acc[4];
#pragma unroll
  for (int t = 0; t < 4; ++t)
#pragma unroll
    for (int i = 0; i < 16; ++i) acc[t][i] = 0.f;
#pragma unroll 2
  for (int s = 0; s < 16; ++s) {
    bf16x8 a = ldbf16x8(Ap + s * 16);
#pragma unroll
    for (int t = 0; t < 4; ++t) {
      bf16x8 b = ldbf16x8(Bp + (size_t)t * 8192 + s * 512);
      acc[t] = __builtin_amdgcn_mfma_f32_32x32x16_bf16(a, b, acc[t], 0, 0, 0);
    }
  }
#pragma unroll
  for (int t = 0; t < 4; ++t) {
    const int co = co0 + t * 32 + lc;
    const float bo = bout[co];
    float* __restrict__ ocol =
        out + ((size_t)(g * 256 + co)) * NP + p0 + 4 * half;
#pragma unroll
    for (int rg = 0; rg < 4; ++rg) {
      float4 v = {acc[t][rg * 4 + 0] + bo, acc[t][rg * 4 + 1] + bo,
                  acc[t][rg * 4 + 2] + bo, acc[t][rg * 4 + 3] + bo};
      *(float4*)(ocol + rg * 8) = v;
    }
  }
}

// ---------------------------------------------------------------------------
// Fallback tier 2: fp32 split-K Gram (known-good).
__global__ __launch_bounds__(256)
void k1_gram(const float* __restrict__ x, float* __restrict__ Cpart) {
  __shared__ float As[32 * 132];
  __shared__ float Bs[32 * 132];
  const int kc = blockIdx.x, ty = blockIdx.y, g = blockIdx.z;
  const int i0 = (ty == 2) ? 128 : 0;
  const int j0 = (ty == 0) ? 0 : 128;
  const float* __restrict__ Xg = x + (size_t)g * 256 * NP;
  const int tid = threadIdx.x, lane = tid & 63, w = tid >> 6;
  const int wy = (w >> 1) * 64, wx = (w & 1) * 64;
  const int ly = (lane >> 3) * 8, lx = (lane & 7) * 8;
  float acc[8][8];
#pragma unroll
  for (int e = 0; e < 8; ++e)
#pragma unroll
    for (int f = 0; f < 8; ++f) acc[e][f] = 0.f;
  const int k8 = (tid & 3) * 8, rowb = tid >> 2, k0 = kc * 256;
  for (int s = 0; s < 8; ++s) {
    const int ks = k0 + s * 32;
#pragma unroll
    for (int pass = 0; pass < 2; ++pass) {
      const int row = rowb + pass * 64;
      const size_t ea = (size_t)(i0 + row) * NP + ks + k8;
      float4 a = *(const float4*)(Xg + ea);
      float4 b = *(const float4*)(Xg + ea + 4);
      As[(k8+0)*132+row]=a.x; As[(k8+1)*132+row]=a.y;
      As[(k8+2)*132+row]=a.z; As[(k8+3)*132+row]=a.w;
      As[(k8+4)*132+row]=b.x; As[(k8+5)*132+row]=b.y;
      As[(k8+6)*132+row]=b.z; As[(k8+7)*132+row]=b.w;
      const size_t eb = (size_t)(j0 + row) * NP + ks + k8;
      a = *(const float4*)(Xg + eb);
      b = *(const float4*)(Xg + eb + 4);
      Bs[(k8+0)*132+row]=a.x; Bs[(k8+1)*132+row]=a.y;
      Bs[(k8+2)*132+row]=a.z; Bs[(k8+3)*132+row]=a.w;
      Bs[(k8+4)*132+row]=b.x; Bs[(k8+5)*132+row]=b.y;
      Bs[(k8+6)*132+row]=b.z; Bs[(k8+7)*132+row]=b.w;
    }
    __syncthreads();
#pragma unroll 4
    for (int kk = 0; kk < 32; ++kk) {
      const float* ar = &As[kk * 132 + wy + ly];
      const float* br = &Bs[kk * 132 + wx + lx];
      float4 a0 = *(const float4*)(ar), a1 = *(const float4*)(ar + 4);
      float4 b0 = *(const float4*)(br), b1 = *(const float4*)(br + 4);
      const float av[8] = {a0.x,a0.y,a0.z,a0.w,a1.x,a1.y,a1.z,a1.w};
      const float bv[8] = {b0.x,b0.y,b0.z,b0.w,b1.x,b1.y,b1.z,b1.w};
#pragma unroll
      for (int e = 0; e < 8; ++e)
#pragma unroll
        for (int f = 0; f < 8; ++f) acc[e][f] += av[e] * bv[f];
    }
    __syncthreads();
  }
  float* __restrict__ P = Cpart + (((size_t)g * 3 + ty) * 64 + kc) * 16384;
#pragma unroll
  for (int e = 0; e < 8; ++e) {
    float* pr = P + (size_t)(wy + ly + e) * 128 + wx + lx;
    float4 s0 = {acc[e][0], acc[e][1], acc[e][2], acc[e][3]};
    float4 s1 = {acc[e][4], acc[e][5], acc[e][6], acc[e][7]};
    *(float4*)(pr)     = s0;
    *(float4*)(pr + 4) = s1;
  }
}

__global__ __launch_bounds__(256)
void k1b_reduce(const float* __restrict__ Cpart, float* __restrict__ Cmat) {
  const int sl = blockIdx.x, ty = blockIdx.y, g = blockIdx.z;
  const int ele = sl * 256 + threadIdx.x;
  const float* __restrict__ P =
      Cpart + (((size_t)g * 3 + ty) * 64) * 16384 + ele;
  float v = 0.f;
#pragma unroll 8
  for (int kc = 0; kc < 64; ++kc) v += P[(size_t)kc * 16384];
  const int i0 = (ty == 2) ? 128 : 0;
  const int j0 = (ty == 0) ? 0 : 128;
  const int i = ele >> 7, j = ele & 127;
  float* Cg = Cmat + (size_t)g * 65536;
  Cg[(size_t)(i0 + i) * 256 + (j0 + j)] = v;
  if (ty == 1) Cg[(size_t)(j0 + j) * 256 + (i0 + i)] = v;
}

// Fallback tier 3 (tiny ws): atomic Gram.
__global__ __launch_bounds__(256)
void k1_gram_atomic(const float* __restrict__ x, float* __restrict__ Cmat) {
  __shared__ float As[32 * 132];
  __shared__ float Bs[32 * 132];
  const int kc = blockIdx.x, ty = blockIdx.y, g = blockIdx.z;
  const int i0 = (ty == 2) ? 128 : 0;
  const int j0 = (ty == 0) ? 0 : 128;
  const float* __restrict__ Xg = x + (size_t)g * 256 * NP;
  const int tid = threadIdx.x, lane = tid & 63, w = tid >> 6;
  const int wy = (w >> 1) * 64, wx = (w & 1) * 64;
  const int ly = (lane >> 3) * 8, lx = (lane & 7) * 8;
  float acc[8][8];
#pragma unroll
  for (int e = 0; e < 8; ++e)
#pragma unroll
    for (int f = 0; f < 8; ++f) acc[e][f] = 0.f;
  const int k8 = (tid & 3) * 8, rowb = tid >> 2, k0 = kc * 256;
  for (int s = 0; s < 8; ++s) {
    const int ks = k0 + s * 32;
#pragma unroll
    for (int pass = 0; pass < 2; ++pass) {
      const int row = rowb + pass * 64;
      const size_t ea = (size_t)(i0 + row) * NP + ks + k8;
      float4 a = *(const float4*)(Xg + ea);
      float4 b = *(const float4*)(Xg + ea + 4);
      As[(k8+0)*132+row]=a.x; As[(k8+1)*132+row]=a.y;
      As[(k8+2)*132+row]=a.z; As[(k8+3)*132+row]=a.w;
      As[(k8+4)*132+row]=b.x; As[(k8+5)*132+row]=b.y;
      As[(k8+6)*132+row]=b.z; As[(k8+7)*132+row]=b.w;
      const size_t eb = (size_t)(j0 + row) * NP + ks + k8;
      a = *(const float4*)(Xg + eb);
      b = *(const float4*)(Xg + eb + 4);
      Bs[(k8+0)*132+row]=a.x; Bs[(k8+1)*132+row]=a.y;
      Bs[(k8+2)*132+row]=a.z; Bs[(k8+3)*132+row]=a.w;
      Bs[(k8+4)*132+row]=b.x; Bs[(k8+5)*132+row]=b.y;
      Bs[(k8+6)*132+row]=b.z; Bs[(k8+7)*132+row]=b.w;
    }
    __syncthreads();
#pragma unroll 4
    for (int kk = 0; kk < 32; ++kk) {
      const float* ar = &As[kk * 132 + wy + ly];
      const float* br = &Bs[kk * 132 + wx + lx];
      float4 a0 = *(const float4*)(ar), a1 = *(const float4*)(ar + 4);
      float4 b0 = *(const float4*)(br), b1 = *(const float4*)(br + 4);
      const float av[8] = {a0.x,a0.y,a0.z,a0.w,a1.x,a1.y,a1.z,a1.w};
      const float bv[8] = {b0.x,b0.y,b0.z,b0.w,b1.x,b1.y,b1.z,b1.w};
#pragma unroll
      for (int e = 0; e < 8; ++e)
#pragma unroll
        for (int f = 0; f < 8; ++f) acc[e][f] += av[e] * bv[f];
    }
    __syncthreads();
  }
  float* Cg = Cmat + (size_t)g * 65536;
#pragma unroll
  for (int e = 0; e < 8; ++e)
#pragma unroll
    for (int f = 0; f < 8; ++f) {
      atomicAdd(&Cg[(i0+wy+ly+e)*256 + (j0+wx+lx+f)], acc[e][f]);
      if (ty == 1)
        atomicAdd(&Cg[(j0+wx+lx+f)*256 + (i0+wy+ly+e)], acc[e][f]);
    }
}

// ---------------------------------------------------------------------------
// Fallback middle chain (tiers 2/3).
__global__ __launch_bounds__(256) void k2_T(const float* __restrict__ Wq,
                                            const float* __restrict__ Cmat,
                                            float* __restrict__ T) {
  const int bh = blockIdx.x;
  const int ic = blockIdx.y;
  const int g = bh >> 3, hh = bh & 7;
  const int tid = threadIdx.x;
  const float* __restrict__ Cg = Cmat + (size_t)g * 65536;
  const int r0 = hh * 64 + ic * 4;
  float acc[4] = {0.f, 0.f, 0.f, 0.f};
#pragma unroll 8
  for (int b = 0; b < 256; ++b) {
    const float cv = Cg[(size_t)b * 256 + tid];
#pragma unroll
    for (int ii = 0; ii < 4; ++ii)
      acc[ii] += Wq[(size_t)(r0 + ii) * 256 + b] * cv;
  }
#pragma unroll
  for (int ii = 0; ii < 4; ++ii)
    T[((size_t)bh * 64 + ic * 4 + ii) * 256 + tid] = acc[ii];
}

__global__ __launch_bounds__(256) void k3_sim(const float* __restrict__ Wkv,
                                              const float* __restrict__ T,
                                              float* __restrict__ simattn) {
  __shared__ float Ts[64 * 256];
  const int bh = blockIdx.x;
  const int jc = blockIdx.y;
  const int hh = bh & 7;
  const int tid = threadIdx.x;
  {
    const int f4i = tid & 63;
    const int rwb = tid >> 6;
    for (int pass = 0; pass < 16; ++pass) {
      const int row = rwb + pass * 4;
      float4 v = *(const float4*)(T + ((size_t)bh * 64 + row) * 256 + f4i * 4);
      const int a0 = f4i * 4;
      const float vv[4] = {v.x, v.y, v.z, v.w};
#pragma unroll
      for (int e = 0; e < 4; ++e) {
        const int a = a0 + e;
        Ts[row * 256 + (a & ~31) + ((a + row) & 31)] = vv[e];
      }
    }
  }
  __syncthreads();
  const int i  = tid & 63;
  const int jq = tid >> 6;
  const int jb = jc * 16 + jq * 4;
  float acc[4] = {0.f, 0.f, 0.f, 0.f};
#pragma unroll 4
  for (int a = 0; a < 256; ++a) {
    const float tv = Ts[i * 256 + (a & ~31) + ((a + i) & 31)];
#pragma unroll
    for (int jj = 0; jj < 4; ++jj)
      acc[jj] += Wkv[(size_t)(hh * 64 + jb + jj) * 256 + a] * tv;
  }
#pragma unroll
  for (int jj = 0; jj < 4; ++jj)
    simattn[((size_t)bh * 64 + i) * 64 + jb + jj] = acc[jj] * 0.125f;
}

__global__ __launch_bounds__(64) void k3b_softmax(float* __restrict__ simattn) {
  const int bh = blockIdx.x;
  const int i  = threadIdx.x;
  float* row = simattn + ((size_t)bh * 64 + i) * 64;
  float v[64];
  float m = -1e30f;
#pragma unroll
  for (int j = 0; j < 64; ++j) { v[j] = row[j]; m = fmaxf(m, v[j]); }
  float s = 0.f;
#pragma unroll
  for (int j = 0; j < 64; ++j) { v[j] = __expf(v[j] - m); s += v[j]; }
  const float inv = 1.0f / s;
#pragma unroll
  for (int j = 0; j < 64; ++j) row[j] = v[j] * inv;
}

__global__ __launch_bounds__(256) void k4_we(const float* __restrict__ Wout,
                                             const float* __restrict__ attn,
                                             float* __restrict__ WeT) {
  __shared__ float WL[256 * 64];
  const int jc = blockIdx.x;
  const int hh = blockIdx.y;
  const int g  = blockIdx.z;
  const int bh = g * 8 + hh;
  const int tid = threadIdx.x;
  {
    const int f4i = tid & 15;
    const int cb  = tid >> 4;
    for (int pass = 0; pass < 16; ++pass) {
      const int co = cb + pass * 16;
      float4 v = *(const float4*)(Wout + (size_t)co * 512 + hh * 64 + f4i * 4);
      const int a0 = f4i * 4;
      const float vv[4] = {v.x, v.y, v.z, v.w};
#pragma unroll
      for (int e = 0; e < 4; ++e)
        WL[co * 64 + ((a0 + e + co) & 63)] = vv[e];
    }
  }
  __syncthreads();
  const int jb = jc * 8;
  float acc[8] = {0.f, 0.f, 0.f, 0.f, 0.f, 0.f, 0.f, 0.f};
#pragma unroll 4
  for (int i = 0; i < 64; ++i) {
    const float wv = WL[tid * 64 + ((i + tid) & 63)];
#pragma unroll
    for (int je = 0; je < 8; ++je)
      acc[je] += attn[((size_t)bh * 64 + i) * 64 + jb + je] * wv;
  }
#pragma unroll
  for (int je = 0; je < 8; ++je)
    WeT[(size_t)g * 131072 + (size_t)(hh * 64 + jb + je) * 256 + tid] =
        acc[je];
}

__global__ __launch_bounds__(256)
void k5a_part(const float* __restrict__ Wkv, const float* __restrict__ WeT,
              float* __restrict__ Mp) {
  const int bc = blockIdx.x;
  const int oc = blockIdx.y;
  const int g  = blockIdx.z;
  const int tid = threadIdx.x;
  const int b0 = bc * 4;
  const float* __restrict__ Weg = WeT + (size_t)g * 131072;
  float acc[4] = {0.f, 0.f, 0.f, 0.f};
#pragma unroll 8
  for (int u = 0; u < 32; ++u) {
    const int o = oc * 32 + u;
    const float wv = Weg[(size_t)o * 256 + tid];
    const float* __restrict__ vr = Wkv + (size_t)(512 + o) * 256 + b0;
    acc[0] += vr[0] * wv;
    acc[1] += vr[1] * wv;
    acc[2] += vr[2] * wv;
    acc[3] += vr[3] * wv;
  }
#pragma unroll
  for (int be = 0; be < 4; ++be)
    Mp[(((size_t)g * 16 + oc) * 256 + b0 + be) * 256 + tid] = acc[be];
}

__global__ __launch_bounds__(256)
void k5b_red(const float* __restrict__ Mp, float* __restrict__ Mt,
             u16* __restrict__ MA) {
  const int b = blockIdx.x;
  const int g = blockIdx.y;
  const int tid = threadIdx.x;
  const float* __restrict__ P =
      Mp + ((size_t)g * 16 * 256 + b) * 256 + tid;
  float v = 0.f;
#pragma unroll
  for (int oc = 0; oc < 16; ++oc) v += P[(size_t)oc * 65536];
  Mt[(size_t)g * 65536 + (size_t)b * 256 + tid] = v;
  MA[(size_t)g * 65536 + (size_t)tid * 256 + b] = f2bf(v);
}

__global__ __launch_bounds__(256) void k5_serial(const float* __restrict__ Wkv,
                                                 const float* __restrict__ WeT,
                                                 float* __restrict__ Mt,
                                                 u16* __restrict__ MA) {
  const int bc = blockIdx.x;
  const int g  = blockIdx.y;
  const int tid = threadIdx.x;
  const int b0 = bc * 4;
  const float* __restrict__ Weg = WeT + (size_t)g * 131072;
  float acc[4] = {0.f, 0.f, 0.f, 0.f};
#pragma unroll 4
  for (int o = 0; o < 512; ++o) {
    const float wv = Weg[(size_t)o * 256 + tid];
    const float* __restrict__ vr = Wkv + (size_t)(512 + o) * 256 + b0;
    acc[0] += vr[0] * wv;
    acc[1] += vr[1] * wv;
    acc[2] += vr[2] * wv;
    acc[3] += vr[3] * wv;
  }
#pragma unroll
  for (int be = 0; be < 4; ++be) {
    Mt[(size_t)g * 65536 + (size_t)(b0 + be) * 256 + tid] = acc[be];
    MA[(size_t)g * 65536 + (size_t)tid * 256 + b0 + be] = f2bf(acc[be]);
  }
}

// Fallback fp32 K6.
__global__ __launch_bounds__(256)
void k6_apply(const float* __restrict__ x, const float* __restrict__ Mt,
              const float* __restrict__ bout, float* __restrict__ out) {
  __shared__ float As[32 * 132];
  __shared__ float Bs[32 * 132];
  const int pc = blockIdx.x;
  const int oy = blockIdx.y;
  const int g  = blockIdx.z;
  const int p0 = pc * 128;
  const int o0 = oy * 128;
  const float* __restrict__ Xg = x + (size_t)g * 256 * NP;
  const float* __restrict__ Mg = Mt + (size_t)g * 65536;
  const int tid  = threadIdx.x;
  const int lane = tid & 63;
  const int w    = tid >> 6;
  const int wy = (w >> 1) * 64;
  const int wx = (w & 1) * 64;
  const int ly = (lane >> 3) * 8;
  const int lx = (lane & 7) * 8;
  float acc[8][8];
#pragma unroll
  for (int e = 0; e < 8; ++e)
#pragma unroll
    for (int f = 0; f < 8; ++f) acc[e][f] = 0.f;
  const int c4 = (tid & 31) * 4;
  const int kb = tid >> 5;
  for (int s = 0; s < 8; ++s) {
#pragma unroll
    for (int r = 0; r < 4; ++r) {
      const int kk = kb + r * 8;
      const int f  = s * 32 + kk;
      *(float4*)&As[kk * 132 + c4] =
          *(const float4*)(Mg + (size_t)f * 256 + o0 + c4);
      *(float4*)&Bs[kk * 132 + c4] =
          *(const float4*)(Xg + (size_t)f * NP + p0 + c4);
    }
    __syncthreads();
#pragma unroll 4
    for (int kk = 0; kk < 32; ++kk) {
      const float* __restrict__ ar = &As[kk * 132 + wy + ly];
      const float* __restrict__ br = &Bs[kk * 132 + wx + lx];
      float4 a0 = *(const float4*)(ar);
      float4 a1 = *(const float4*)(ar + 4);
      float4 b0 = *(const float4*)(br);
      float4 b1 = *(const float4*)(br + 4);
      const float av[8] = {a0.x, a0.y, a0.z, a0.w, a1.x, a1.y, a1.z, a1.w};
      const float bv[8] = {b0.x, b0.y, b0.z, b0.w, b1.x, b1.y, b1.z, b1.w};
#pragma unroll
      for (int e = 0; e < 8; ++e)
#pragma unroll
        for (int f = 0; f < 8; ++f) acc[e][f] += av[e] * bv[f];
    }
    __syncthreads();
  }
#pragma unroll
  for (int e = 0; e < 8; ++e) {
    const int co = o0 + wy + ly + e;
    const float bo = bout[co];
    float* __restrict__ orow =
        out + ((size_t)(g * 256 + co)) * NP + p0 + wx + lx;
    float4 s0 = {acc[e][0] + bo, acc[e][1] + bo, acc[e][2] + bo,
                 acc[e][3] + bo};
    float4 s1 = {acc[e][4] + bo, acc[e][5] + bo, acc[e][6] + bo,
                 acc[e][7] + bo};
    *(float4*)(orow)     = s0;
    *(float4*)(orow + 4) = s1;
  }
}

// ---------------------------------------------------------------------------
extern "C" void kernel_launch(void* const* d_in, const int* in_sizes, int n_in,
                              void* d_out, int out_size, void* d_ws,
                              size_t ws_size, hipStream_t stream) {
  const float* x    = (const float*)d_in[0];
  const float* Wq   = (const float*)d_in[1];
  const float* Wkv  = (const float*)d_in[2];
  const float* Wout = (const float*)d_in[3];
  const float* bout = (const float*)d_in[4];
  float* out = (float*)d_out;
  float* ws  = (float*)d_ws;

  float* C    = ws + OFF_C;
  float* T    = ws + OFF_T;
  float* att  = ws + OFF_AT;
  float* WeT  = ws + OFF_WE;
  float* Mt   = ws + OFF_MT;
  u16*   MA   = (u16*)(ws + OFF_MA);
  u16*   Xb   = (u16*)(ws + OFF_XB);
  float* Cp1  = ws + OFF_CP1;
  float* Cp2  = ws + OFF_CP2;

  const bool mfma_path = (ws_size >= NEED1);
  const bool splitk    = (ws_size >= NEED2);

  if (mfma_path) {
    // 6-node graph: k0 -> k1 -> k1b -> kA -> kBC -> k6
    k0_cvt<<<dim3(256, 2), 256, 0, stream>>>(x, Xb);
    k1_mfma<<<dim3(4, 32, 2), 256, 0, stream>>>(Xb, Cp1);
    k1b_red<<<dim3(64, 4, 2), 256, 0, stream>>>(Cp1, C);
    kA_attn<<<dim3(16, 16), 256, 0, stream>>>(Wq, Wkv, C, att);
    kBC_m<<<dim3(32, 2), 256, 0, stream>>>(Wout, Wkv, att, MA);
    k6_mfma<<<dim3(128, 2, 2), 256, 0, stream>>>(Xb, MA, bout, out);
    return;
  }

  // Fallback tiers (original chain).
  if (splitk) {
    k1_gram<<<dim3(64, 3, 2), 256, 0, stream>>>(x, Cp2);
    k1b_reduce<<<dim3(64, 3, 2), 256, 0, stream>>>(Cp2, C);
  } else {
    hipMemsetAsync(C, 0, 131072 * sizeof(float), stream);
    k1_gram_atomic<<<dim3(64, 3, 2), 256, 0, stream>>>(x, C);
  }
  k2_T<<<dim3(16, 16), 256, 0, stream>>>(Wq, C, T);
  k3_sim<<<dim3(16, 4), 256, 0, stream>>>(Wkv, T, att);
  k3b_softmax<<<dim3(16), 64, 0, stream>>>(att);
  k4_we<<<dim3(8, 8, 2), 256, 0, stream>>>(Wout, att, WeT);
  if (splitk) {
    k5a_part<<<dim3(64, 16, 2), 256, 0, stream>>>(Wkv, WeT, Cp2);
    k5b_red<<<dim3(256, 2), 256, 0, stream>>>(Cp2, Mt, MA);
  } else {
    k5_serial<<<dim3(64, 2), 256, 0, stream>>>(Wkv, WeT, Mt, MA);
  }
  k6_apply<<<dim3(128, 2, 2), 256, 0, stream>>>(x, Mt, bout, out);
}

// Round 8
// 156.336 us; speedup vs baseline: 3.1445x; 1.2438x over previous
//
#include <hip/hip_runtime.h>
#include <cstdint>
#include <cstddef>

using u16 = unsigned short;
using u32 = unsigned int;

typedef __attribute__((ext_vector_type(8))) short bf16x8;   // 8 bf16 = 4 VGPRs
typedef __attribute__((ext_vector_type(16))) float f32x16;  // MFMA 32x32 acc

__device__ __forceinline__ u16 f2bf(float f) {  // round-to-nearest-even
  union { float f; u32 i; } x; x.f = f;
  u32 r = (x.i + 0x7FFFu + ((x.i >> 16) & 1u)) >> 16;
  return (u16)r;
}
__device__ __forceinline__ bf16x8 ldbf16x8(const u16* p) {
  union { uint4 u; bf16x8 v; } t;
  t.u = *(const uint4*)p;
  return t.v;
}

// Geometry: x (16,32,128,128) fp32 -> G=2 groups, F=256 features/group,
// N=16384 positions, 8 heads/group, dim_head=64.  Collapse:
// C[g]=F·F^T Gram; sim=Wq_h·C·Wk_h^T; attn=softmax; M=(Wout·bd(attn))·Wv;
// out = M·f + bout.
constexpr int NP = 16384;

// Fragment-tiled bf16 layouts: element (row, k) lives at
//   [panel=row>>5][s=k>>4][h=(k>>3)&1][lc=row&31][j=k&7]
// XbF  : rows=256 f,  k=16384 p   -> panel stride 524288 (u16 units)
// MAF  : rows=256 co, k=256 f(=b) -> panel stride 8192
// (XbT eliminated: k6 transposes XbF tiles in LDS — R7-verified, ~-27 us.)

// ws layout (fp32 element offsets)
constexpr size_t OFF_C   = 0;        // C[2][256][256]        131072
constexpr size_t OFF_T   = 131072;   // T (fallback)          262144
constexpr size_t OFF_AT  = 393216;   // sim/attn[16][64][64]   65536
constexpr size_t OFF_WE  = 458752;   // WeT (fallback)        262144
constexpr size_t OFF_MT  = 720896;   // Mt (fallback)         131072
constexpr size_t OFF_MA  = 851968;   // MAF bf16 [2][...]     (65536 fl)
constexpr size_t OFF_XB  = 917504;   // XbF  bf16 [2][...]    (4194304 fl)
constexpr size_t OFF_CP1 = 5111808;  // Cpart1 [2][4tp][32kc][16384] (4194304)
                                     // reused after k1b as Mp[2][8h][256co][256b]
constexpr size_t NEED1   = (OFF_CP1 + 4194304) * 4;  // 37,224,448 B
constexpr size_t OFF_CP2 = 851968;   // fp32-fallback partials (6291456 fl)
constexpr size_t NEED2   = (OFF_CP2 + 6291456) * 4;  // 28,573,696 B

// ---------------------------------------------------------------------------
// K0 (R7-verified): x fp32 -> XbF only.  Pure streaming convert, no LDS.
__global__ __launch_bounds__(256)
void k0_cvt(const float* __restrict__ x, u16* __restrict__ XbF) {
  const int pc = blockIdx.x;   // 256 chunks of 64 positions
  const int g  = blockIdx.y;
  const int p0 = pc * 64;
  const float* __restrict__ Xg = x + (size_t)g * 256 * NP;
  u16* __restrict__ XbFg = XbF + (size_t)g * 256 * NP;
  const int tid = threadIdx.x;
  const int f8i = tid & 7, rb = tid >> 3;
  const int sA = pc * 4 + (f8i >> 1);   // k-step (p>>4)
  const int hA = f8i & 1;               // (p>>3)&1
#pragma unroll
  for (int pass = 0; pass < 8; ++pass) {
    const int row = rb + pass * 32;
    const size_t e0 = (size_t)row * NP + p0 + f8i * 8;
    float4 a = *(const float4*)(Xg + e0);
    float4 b = *(const float4*)(Xg + e0 + 4);
    uint4 s;
    s.x = (u32)f2bf(a.x) | ((u32)f2bf(a.y) << 16);
    s.y = (u32)f2bf(a.z) | ((u32)f2bf(a.w) << 16);
    s.z = (u32)f2bf(b.x) | ((u32)f2bf(b.y) << 16);
    s.w = (u32)f2bf(b.z) | ((u32)f2bf(b.w) << 16);
    const int panel = row >> 5, lc = row & 31;
    *(uint4*)(XbFg + (size_t)panel * 524288 + sA * 512 + hA * 256 + lc * 8) = s;
  }
}

// ---------------------------------------------------------------------------
// K1 (MFMA): 128x128 output tiles (2x2 grid); 4 loads feed 4 MFMAs.
__global__ __launch_bounds__(256)
void k1_mfma(const u16* __restrict__ XbF, float* __restrict__ Cpart) {
  const int tp = blockIdx.x;   // 4 tile positions (2x2 of 128x128)
  const int kc = blockIdx.y;   // 32 chunks of 512 positions
  const int g  = blockIdx.z;
  const int ti = tp >> 1, tj = tp & 1;
  const int tid = threadIdx.x;
  const int w = tid >> 6, half = (tid >> 5) & 1, lc = tid & 31;
  const int qi = w >> 1, qj = w & 1;    // 64x64 quadrant per wave
  const u16* __restrict__ Xg = XbF + (size_t)g * 256 * NP;
  const size_t koff = (size_t)kc * 16384 + half * 256 + lc * 8;
  const u16* A0 = Xg + (size_t)(ti * 4 + qi * 2 + 0) * 524288 + koff;
  const u16* A1 = Xg + (size_t)(ti * 4 + qi * 2 + 1) * 524288 + koff;
  const u16* B0 = Xg + (size_t)(tj * 4 + qj * 2 + 0) * 524288 + koff;
  const u16* B1 = Xg + (size_t)(tj * 4 + qj * 2 + 1) * 524288 + koff;
  f32x16 acc00, acc01, acc10, acc11;
#pragma unroll
  for (int i = 0; i < 16; ++i) {
    acc00[i] = 0.f; acc01[i] = 0.f; acc10[i] = 0.f; acc11[i] = 0.f;
  }
#pragma unroll 4
  for (int s = 0; s < 32; ++s) {
    bf16x8 a0 = ldbf16x8(A0 + s * 512);
    bf16x8 a1 = ldbf16x8(A1 + s * 512);
    bf16x8 b0 = ldbf16x8(B0 + s * 512);
    bf16x8 b1 = ldbf16x8(B1 + s * 512);
    acc00 = __builtin_amdgcn_mfma_f32_32x32x16_bf16(a0, b0, acc00, 0, 0, 0);
    acc01 = __builtin_amdgcn_mfma_f32_32x32x16_bf16(a0, b1, acc01, 0, 0, 0);
    acc10 = __builtin_amdgcn_mfma_f32_32x32x16_bf16(a1, b0, acc10, 0, 0, 0);
    acc11 = __builtin_amdgcn_mfma_f32_32x32x16_bf16(a1, b1, acc11, 0, 0, 0);
  }
  float* __restrict__ P = Cpart + (((size_t)g * 4 + tp) * 32 + kc) * 16384;
#pragma unroll
  for (int r = 0; r < 16; ++r) {
    const int rr = (r & 3) + 8 * (r >> 2) + 4 * half;
    const int row0 = qi * 64 + rr, col0 = qj * 64 + lc;
    P[(row0 +  0) * 128 + col0 +  0] = acc00[r];
    P[(row0 +  0) * 128 + col0 + 32] = acc01[r];
    P[(row0 + 32) * 128 + col0 +  0] = acc10[r];
    P[(row0 + 32) * 128 + col0 + 32] = acc11[r];
  }
}

// K1b: sum 32 K-chunk partials per 128x128 tile -> C.
__global__ __launch_bounds__(256)
void k1b_red(const float* __restrict__ Cpart, float* __restrict__ Cmat) {
  const int sl = blockIdx.x;   // 64 slices of 256
  const int tp = blockIdx.y;   // 4
  const int g  = blockIdx.z;
  const int ele = sl * 256 + threadIdx.x;
  const float* __restrict__ P =
      Cpart + (((size_t)g * 4 + tp) * 32) * 16384 + ele;
  float v = 0.f;
#pragma unroll
  for (int kc = 0; kc < 32; ++kc) v += P[(size_t)kc * 16384];
  const int ti = tp >> 1, tj = tp & 1;
  const int i = ele >> 7, j = ele & 127;
  Cmat[(size_t)g * 65536 + (size_t)(ti * 128 + i) * 256 + tj * 128 + j] = v;
}

// ---------------------------------------------------------------------------
// kA (fused k2+k3+k3b): per (bh, ic=4-row chunk): T rows -> sim -> softmax.
__global__ __launch_bounds__(256)
void kA_attn(const float* __restrict__ Wq, const float* __restrict__ Wkv,
             const float* __restrict__ Cmat, float* __restrict__ attn) {
  __shared__ float WqL[4 * 256];
  __shared__ float Ts[4 * 256];
  const int bh = blockIdx.x;   // 16
  const int ic = blockIdx.y;   // 16 chunks of 4 i-rows
  const int g = bh >> 3, hh = bh & 7;
  const int tid = threadIdx.x;
  const float* __restrict__ Cg = Cmat + (size_t)g * 65536;
  {
    const int r = tid >> 6, c4 = (tid & 63) * 4;
    *(float4*)(&WqL[r * 256 + c4]) =
        *(const float4*)(Wq + (size_t)(hh * 64 + ic * 4 + r) * 256 + c4);
  }
  __syncthreads();
  float acc[4] = {0.f, 0.f, 0.f, 0.f};
#pragma unroll 8
  for (int b = 0; b < 256; ++b) {
    const float cv = Cg[(size_t)b * 256 + tid];
#pragma unroll
    for (int r = 0; r < 4; ++r) acc[r] += WqL[r * 256 + b] * cv;
  }
#pragma unroll
  for (int r = 0; r < 4; ++r) Ts[r * 256 + tid] = acc[r];
  __syncthreads();
  const int r = tid >> 6, j = tid & 63;
  const float* __restrict__ Wk = Wkv + (size_t)(hh * 64 + j) * 256;
  float s = 0.f;
#pragma unroll 4
  for (int a4 = 0; a4 < 64; ++a4) {
    float4 w = *(const float4*)(Wk + a4 * 4);
    const float* t4 = &Ts[r * 256 + a4 * 4];
    s += t4[0] * w.x + t4[1] * w.y + t4[2] * w.z + t4[3] * w.w;
  }
  s *= 0.125f;
  float m = s;
#pragma unroll
  for (int off = 32; off; off >>= 1) m = fmaxf(m, __shfl_xor(m, off));
  const float e = __expf(s - m);
  float sum = e;
#pragma unroll
  for (int off = 32; off; off >>= 1) sum += __shfl_xor(sum, off);
  attn[((size_t)bh * 64 + ic * 4 + r) * 64 + j] = e / sum;
}

// ---------------------------------------------------------------------------
// kB (R4-verified, fused k4+k5a): per (bh, cc=16-co chunk): U = Wout·attn,
// then Mp[g][hh][co][b] = sum_j U[co][j]·Wv[hh*64+j][b].  256 blocks.
__global__ __launch_bounds__(256)
void kB_m(const float* __restrict__ Wout, const float* __restrict__ Wkv,
          const float* __restrict__ attn, float* __restrict__ Mp) {
  __shared__ float AtL[64 * 64];   // attn[i][j]
  __shared__ float WoL[16 * 64];   // Wout[co_l][i]
  __shared__ float UL[16 * 64];    // U[co_l][j]
  const int bh = blockIdx.x;  // 16
  const int cc = blockIdx.y;  // 16 chunks of 16 co
  const int g = bh >> 3, hh = bh & 7;
  const int tid = threadIdx.x;
  {  // stage attn (coalesced float4)
    const float* __restrict__ A = attn + (size_t)bh * 4096;
#pragma unroll
    for (int q = 0; q < 4; ++q)
      *(float4*)(&AtL[q * 1024 + tid * 4]) =
          *(const float4*)(A + q * 1024 + tid * 4);
  }
  {  // stage Wout chunk: rows cc*16..+16, cols hh*64..+64
    const int co_l = tid >> 4, i4 = (tid & 15) * 4;
    *(float4*)(&WoL[co_l * 64 + i4]) =
        *(const float4*)(Wout + (size_t)(cc * 16 + co_l) * 512 + hh * 64 + i4);
  }
  __syncthreads();
  // phase 1: U[cw*4+u][j]; j = tid&63, cw = tid>>6
  const int j = tid & 63, cw = tid >> 6;
  float u4[4] = {0.f, 0.f, 0.f, 0.f};
#pragma unroll 4
  for (int i = 0; i < 64; ++i) {
    const float av = AtL[i * 64 + j];
#pragma unroll
    for (int u = 0; u < 4; ++u) u4[u] += WoL[(cw * 4 + u) * 64 + i] * av;
  }
  __syncthreads();
#pragma unroll
  for (int u = 0; u < 4; ++u) UL[(cw * 4 + u) * 64 + j] = u4[u];
  __syncthreads();
  // phase 2: thread = b; 16 co accumulators
  float acc[16];
#pragma unroll
  for (int c = 0; c < 16; ++c) acc[c] = 0.f;
#pragma unroll 4
  for (int j2 = 0; j2 < 64; ++j2) {
    const float wv = Wkv[(size_t)(512 + hh * 64 + j2) * 256 + tid];
#pragma unroll
    for (int c = 0; c < 16; ++c) acc[c] += UL[c * 64 + j2] * wv;
  }
  float* __restrict__ P =
      Mp + (((size_t)g * 8 + hh) * 256 + cc * 16) * 256 + tid;
#pragma unroll
  for (int c = 0; c < 16; ++c) P[(size_t)c * 256] = acc[c];
}

// kC (R4-verified): reduce 8 head-partials -> MAF bf16 fragments.  64 blocks.
__global__ __launch_bounds__(256)
void kC_red(const float* __restrict__ Mp, u16* __restrict__ MA) {
  const int panel = blockIdx.x >> 2;  // 8 co-panels of 32
  const int q     = blockIdx.x & 3;
  const int g     = blockIdx.y;
  const int tid = threadIdx.x;
  const float* __restrict__ Pg = Mp + (size_t)g * 8 * 65536;
  u16* __restrict__ Mg = MA + (size_t)g * 65536;
  const int item = tid + q * 256;           // (s*2+h)*32 + lc
  const int lc = item & 31;
  const int co = panel * 32 + lc;
  const int b0 = (item >> 5) * 8;           // s*16 + h*8
  float v[8] = {0.f, 0.f, 0.f, 0.f, 0.f, 0.f, 0.f, 0.f};
#pragma unroll
  for (int hd = 0; hd < 8; ++hd) {
    const float* p = Pg + (size_t)hd * 65536 + (size_t)co * 256 + b0;
    float4 a = *(const float4*)(p);
    float4 b = *(const float4*)(p + 4);
    v[0] += a.x; v[1] += a.y; v[2] += a.z; v[3] += a.w;
    v[4] += b.x; v[5] += b.y; v[6] += b.z; v[7] += b.w;
  }
  uint4 sdat;
  sdat.x = (u32)f2bf(v[0]) | ((u32)f2bf(v[1]) << 16);
  sdat.y = (u32)f2bf(v[2]) | ((u32)f2bf(v[3]) << 16);
  sdat.z = (u32)f2bf(v[4]) | ((u32)f2bf(v[5]) << 16);
  sdat.w = (u32)f2bf(v[6]) | ((u32)f2bf(v[7]) << 16);
  *(uint4*)(Mg + (size_t)panel * 8192 + (size_t)item * 8) = sdat;
}

// ---------------------------------------------------------------------------
// K6 (R7-verified): out[co][p] = sum_f Xb[f][p]*M[co][f] + bout[co].
// A-tile (128p x 256f) staged from XbF into LDS with transpose (once per
// block); fragments then read as clean ds_read_b128.  B = MAF (global).
__global__ __launch_bounds__(256)
void k6_mfma(const u16* __restrict__ XbF, const u16* __restrict__ MA,
             const float* __restrict__ bout, float* __restrict__ out) {
  __shared__ u16 T[128 * 264];   // [p_local][f], stride 264 u16 (16B-aligned)
  const int pb = blockIdx.x;   // 128 p-blocks of 128
  const int cb = blockIdx.y;   // 2 co-blocks of 128
  const int g  = blockIdx.z;
  const int tid = threadIdx.x;
  const u16* __restrict__ Xg = XbF + (size_t)g * 256 * NP;
  for (int it = 0; it < 16; ++it) {
    const int idx = it * 256 + tid;              // uint4 index
    const int pa  = idx >> 9;                    // panel (f>>5)
    const int o2  = (idx & 511) * 8;             // u16 offset within slab
    union { uint4 u; u16 e[8]; } v;
    v.u = *(const uint4*)(Xg + (size_t)pa * 524288 + (size_t)pb * 4096 + o2);
    const int sp_l = o2 >> 9;
    const int r    = o2 & 511;
    const int h    = r >> 8;
    const int lcf  = (r >> 3) & 31;
    const int f    = pa * 32 + lcf;
    const int pl   = sp_l * 16 + h * 8;          // p_local base (8 consec)
#pragma unroll
    for (int jj = 0; jj < 8; ++jj) T[(pl + jj) * 264 + f] = v.e[jj];
  }
  __syncthreads();
  const int w = tid >> 6, half = (tid >> 5) & 1, lc = tid & 31;
  const int p0  = pb * 128 + w * 32;
  const int co0 = cb * 128;
  const u16* __restrict__ Ap = &T[(w * 32 + lc) * 264 + half * 8];
  const u16* __restrict__ Bp = MA + (size_t)g * 65536 +
                               (size_t)cb * 32768 + half * 256 + lc * 8;
  f32x16 acc[4];
#pragma unroll
  for (int t = 0; t < 4; ++t)
#pragma unroll
    for (int i = 0; i < 16; ++i) acc[t][i] = 0.f;
#pragma unroll 2
  for (int s = 0; s < 16; ++s) {
    bf16x8 a = ldbf16x8(Ap + s * 16);
#pragma unroll
    for (int t = 0; t < 4; ++t) {
      bf16x8 b = ldbf16x8(Bp + (size_t)t * 8192 + s * 512);
      acc[t] = __builtin_amdgcn_mfma_f32_32x32x16_bf16(a, b, acc[t], 0, 0, 0);
    }
  }
#pragma unroll
  for (int t = 0; t < 4; ++t) {
    const int co = co0 + t * 32 + lc;
    const float bo = bout[co];
    float* __restrict__ ocol =
        out + ((size_t)(g * 256 + co)) * NP + p0 + 4 * half;
#pragma unroll
    for (int rg = 0; rg < 4; ++rg) {
      float4 v = {acc[t][rg * 4 + 0] + bo, acc[t][rg * 4 + 1] + bo,
                  acc[t][rg * 4 + 2] + bo, acc[t][rg * 4 + 3] + bo};
      *(float4*)(ocol + rg * 8) = v;
    }
  }
}

// ---------------------------------------------------------------------------
// Fallback tier 2: fp32 split-K Gram (known-good).
__global__ __launch_bounds__(256)
void k1_gram(const float* __restrict__ x, float* __restrict__ Cpart) {
  __shared__ float As[32 * 132];
  __shared__ float Bs[32 * 132];
  const int kc = blockIdx.x, ty = blockIdx.y, g = blockIdx.z;
  const int i0 = (ty == 2) ? 128 : 0;
  const int j0 = (ty == 0) ? 0 : 128;
  const float* __restrict__ Xg = x + (size_t)g * 256 * NP;
  const int tid = threadIdx.x, lane = tid & 63, w = tid >> 6;
  const int wy = (w >> 1) * 64, wx = (w & 1) * 64;
  const int ly = (lane >> 3) * 8, lx = (lane & 7) * 8;
  float acc[8][8];
#pragma unroll
  for (int e = 0; e < 8; ++e)
#pragma unroll
    for (int f = 0; f < 8; ++f) acc[e][f] = 0.f;
  const int k8 = (tid & 3) * 8, rowb = tid >> 2, k0 = kc * 256;
  for (int s = 0; s < 8; ++s) {
    const int ks = k0 + s * 32;
#pragma unroll
    for (int pass = 0; pass < 2; ++pass) {
      const int row = rowb + pass * 64;
      const size_t ea = (size_t)(i0 + row) * NP + ks + k8;
      float4 a = *(const float4*)(Xg + ea);
      float4 b = *(const float4*)(Xg + ea + 4);
      As[(k8+0)*132+row]=a.x; As[(k8+1)*132+row]=a.y;
      As[(k8+2)*132+row]=a.z; As[(k8+3)*132+row]=a.w;
      As[(k8+4)*132+row]=b.x; As[(k8+5)*132+row]=b.y;
      As[(k8+6)*132+row]=b.z; As[(k8+7)*132+row]=b.w;
      const size_t eb = (size_t)(j0 + row) * NP + ks + k8;
      a = *(const float4*)(Xg + eb);
      b = *(const float4*)(Xg + eb + 4);
      Bs[(k8+0)*132+row]=a.x; Bs[(k8+1)*132+row]=a.y;
      Bs[(k8+2)*132+row]=a.z; Bs[(k8+3)*132+row]=a.w;
      Bs[(k8+4)*132+row]=b.x; Bs[(k8+5)*132+row]=b.y;
      Bs[(k8+6)*132+row]=b.z; Bs[(k8+7)*132+row]=b.w;
    }
    __syncthreads();
#pragma unroll 4
    for (int kk = 0; kk < 32; ++kk) {
      const float* ar = &As[kk * 132 + wy + ly];
      const float* br = &Bs[kk * 132 + wx + lx];
      float4 a0 = *(const float4*)(ar), a1 = *(const float4*)(ar + 4);
      float4 b0 = *(const float4*)(br), b1 = *(const float4*)(br + 4);
      const float av[8] = {a0.x,a0.y,a0.z,a0.w,a1.x,a1.y,a1.z,a1.w};
      const float bv[8] = {b0.x,b0.y,b0.z,b0.w,b1.x,b1.y,b1.z,b1.w};
#pragma unroll
      for (int e = 0; e < 8; ++e)
#pragma unroll
        for (int f = 0; f < 8; ++f) acc[e][f] += av[e] * bv[f];
    }
    __syncthreads();
  }
  float* __restrict__ P = Cpart + (((size_t)g * 3 + ty) * 64 + kc) * 16384;
#pragma unroll
  for (int e = 0; e < 8; ++e) {
    float* pr = P + (size_t)(wy + ly + e) * 128 + wx + lx;
    float4 s0 = {acc[e][0], acc[e][1], acc[e][2], acc[e][3]};
    float4 s1 = {acc[e][4], acc[e][5], acc[e][6], acc[e][7]};
    *(float4*)(pr)     = s0;
    *(float4*)(pr + 4) = s1;
  }
}

__global__ __launch_bounds__(256)
void k1b_reduce(const float* __restrict__ Cpart, float* __restrict__ Cmat) {
  const int sl = blockIdx.x, ty = blockIdx.y, g = blockIdx.z;
  const int ele = sl * 256 + threadIdx.x;
  const float* __restrict__ P =
      Cpart + (((size_t)g * 3 + ty) * 64) * 16384 + ele;
  float v = 0.f;
#pragma unroll 8
  for (int kc = 0; kc < 64; ++kc) v += P[(size_t)kc * 16384];
  const int i0 = (ty == 2) ? 128 : 0;
  const int j0 = (ty == 0) ? 0 : 128;
  const int i = ele >> 7, j = ele & 127;
  float* Cg = Cmat + (size_t)g * 65536;
  Cg[(size_t)(i0 + i) * 256 + (j0 + j)] = v;
  if (ty == 1) Cg[(size_t)(j0 + j) * 256 + (i0 + i)] = v;
}

// Fallback tier 3 (tiny ws): atomic Gram.
__global__ __launch_bounds__(256)
void k1_gram_atomic(const float* __restrict__ x, float* __restrict__ Cmat) {
  __shared__ float As[32 * 132];
  __shared__ float Bs[32 * 132];
  const int kc = blockIdx.x, ty = blockIdx.y, g = blockIdx.z;
  const int i0 = (ty == 2) ? 128 : 0;
  const int j0 = (ty == 0) ? 0 : 128;
  const float* __restrict__ Xg = x + (size_t)g * 256 * NP;
  const int tid = threadIdx.x, lane = tid & 63, w = tid >> 6;
  const int wy = (w >> 1) * 64, wx = (w & 1) * 64;
  const int ly = (lane >> 3) * 8, lx = (lane & 7) * 8;
  float acc[8][8];
#pragma unroll
  for (int e = 0; e < 8; ++e)
#pragma unroll
    for (int f = 0; f < 8; ++f) acc[e][f] = 0.f;
  const int k8 = (tid & 3) * 8, rowb = tid >> 2, k0 = kc * 256;
  for (int s = 0; s < 8; ++s) {
    const int ks = k0 + s * 32;
#pragma unroll
    for (int pass = 0; pass < 2; ++pass) {
      const int row = rowb + pass * 64;
      const size_t ea = (size_t)(i0 + row) * NP + ks + k8;
      float4 a = *(const float4*)(Xg + ea);
      float4 b = *(const float4*)(Xg + ea + 4);
      As[(k8+0)*132+row]=a.x; As[(k8+1)*132+row]=a.y;
      As[(k8+2)*132+row]=a.z; As[(k8+3)*132+row]=a.w;
      As[(k8+4)*132+row]=b.x; As[(k8+5)*132+row]=b.y;
      As[(k8+6)*132+row]=b.z; As[(k8+7)*132+row]=b.w;
      const size_t eb = (size_t)(j0 + row) * NP + ks + k8;
      a = *(const float4*)(Xg + eb);
      b = *(const float4*)(Xg + eb + 4);
      Bs[(k8+0)*132+row]=a.x; Bs[(k8+1)*132+row]=a.y;
      Bs[(k8+2)*132+row]=a.z; Bs[(k8+3)*132+row]=a.w;
      Bs[(k8+4)*132+row]=b.x; Bs[(k8+5)*132+row]=b.y;
      Bs[(k8+6)*132+row]=b.z; Bs[(k8+7)*132+row]=b.w;
    }
    __syncthreads();
#pragma unroll 4
    for (int kk = 0; kk < 32; ++kk) {
      const float* ar = &As[kk * 132 + wy + ly];
      const float* br = &Bs[kk * 132 + wx + lx];
      float4 a0 = *(const float4*)(ar), a1 = *(const float4*)(ar + 4);
      float4 b0 = *(const float4*)(br), b1 = *(const float4*)(br + 4);
      const float av[8] = {a0.x,a0.y,a0.z,a0.w,a1.x,a1.y,a1.z,a1.w};
      const float bv[8] = {b0.x,b0.y,b0.z,b0.w,b1.x,b1.y,b1.z,b1.w};
#pragma unroll
      for (int e = 0; e < 8; ++e)
#pragma unroll
        for (int f = 0; f < 8; ++f) acc[e][f] += av[e] * bv[f];
    }
    __syncthreads();
  }
  float* Cg = Cmat + (size_t)g * 65536;
#pragma unroll
  for (int e = 0; e < 8; ++e)
#pragma unroll
    for (int f = 0; f < 8; ++f) {
      atomicAdd(&Cg[(i0+wy+ly+e)*256 + (j0+wx+lx+f)], acc[e][f]);
      if (ty == 1)
        atomicAdd(&Cg[(j0+wx+lx+f)*256 + (i0+wy+ly+e)], acc[e][f]);
    }
}

// ---------------------------------------------------------------------------
// Fallback middle chain (tiers 2/3).
__global__ __launch_bounds__(256) void k2_T(const float* __restrict__ Wq,
                                            const float* __restrict__ Cmat,
                                            float* __restrict__ T) {
  const int bh = blockIdx.x;
  const int ic = blockIdx.y;
  const int g = bh >> 3, hh = bh & 7;
  const int tid = threadIdx.x;
  const float* __restrict__ Cg = Cmat + (size_t)g * 65536;
  const int r0 = hh * 64 + ic * 4;
  float acc[4] = {0.f, 0.f, 0.f, 0.f};
#pragma unroll 8
  for (int b = 0; b < 256; ++b) {
    const float cv = Cg[(size_t)b * 256 + tid];
#pragma unroll
    for (int ii = 0; ii < 4; ++ii)
      acc[ii] += Wq[(size_t)(r0 + ii) * 256 + b] * cv;
  }
#pragma unroll
  for (int ii = 0; ii < 4; ++ii)
    T[((size_t)bh * 64 + ic * 4 + ii) * 256 + tid] = acc[ii];
}

__global__ __launch_bounds__(256) void k3_sim(const float* __restrict__ Wkv,
                                              const float* __restrict__ T,
                                              float* __restrict__ simattn) {
  __shared__ float Ts[64 * 256];
  const int bh = blockIdx.x;
  const int jc = blockIdx.y;
  const int hh = bh & 7;
  const int tid = threadIdx.x;
  {
    const int f4i = tid & 63;
    const int rwb = tid >> 6;
    for (int pass = 0; pass < 16; ++pass) {
      const int row = rwb + pass * 4;
      float4 v = *(const float4*)(T + ((size_t)bh * 64 + row) * 256 + f4i * 4);
      const int a0 = f4i * 4;
      const float vv[4] = {v.x, v.y, v.z, v.w};
#pragma unroll
      for (int e = 0; e < 4; ++e) {
        const int a = a0 + e;
        Ts[row * 256 + (a & ~31) + ((a + row) & 31)] = vv[e];
      }
    }
  }
  __syncthreads();
  const int i  = tid & 63;
  const int jq = tid >> 6;
  const int jb = jc * 16 + jq * 4;
  float acc[4] = {0.f, 0.f, 0.f, 0.f};
#pragma unroll 4
  for (int a = 0; a < 256; ++a) {
    const float tv = Ts[i * 256 + (a & ~31) + ((a + i) & 31)];
#pragma unroll
    for (int jj = 0; jj < 4; ++jj)
      acc[jj] += Wkv[(size_t)(hh * 64 + jb + jj) * 256 + a] * tv;
  }
#pragma unroll
  for (int jj = 0; jj < 4; ++jj)
    simattn[((size_t)bh * 64 + i) * 64 + jb + jj] = acc[jj] * 0.125f;
}

__global__ __launch_bounds__(64) void k3b_softmax(float* __restrict__ simattn) {
  const int bh = blockIdx.x;
  const int i  = threadIdx.x;
  float* row = simattn + ((size_t)bh * 64 + i) * 64;
  float v[64];
  float m = -1e30f;
#pragma unroll
  for (int j = 0; j < 64; ++j) { v[j] = row[j]; m = fmaxf(m, v[j]); }
  float s = 0.f;
#pragma unroll
  for (int j = 0; j < 64; ++j) { v[j] = __expf(v[j] - m); s += v[j]; }
  const float inv = 1.0f / s;
#pragma unroll
  for (int j = 0; j < 64; ++j) row[j] = v[j] * inv;
}

__global__ __launch_bounds__(256) void k4_we(const float* __restrict__ Wout,
                                             const float* __restrict__ attn,
                                             float* __restrict__ WeT) {
  __shared__ float WL[256 * 64];
  const int jc = blockIdx.x;
  const int hh = blockIdx.y;
  const int g  = blockIdx.z;
  const int bh = g * 8 + hh;
  const int tid = threadIdx.x;
  {
    const int f4i = tid & 15;
    const int cb  = tid >> 4;
    for (int pass = 0; pass < 16; ++pass) {
      const int co = cb + pass * 16;
      float4 v = *(const float4*)(Wout + (size_t)co * 512 + hh * 64 + f4i * 4);
      const int a0 = f4i * 4;
      const float vv[4] = {v.x, v.y, v.z, v.w};
#pragma unroll
      for (int e = 0; e < 4; ++e)
        WL[co * 64 + ((a0 + e + co) & 63)] = vv[e];
    }
  }
  __syncthreads();
  const int jb = jc * 8;
  float acc[8] = {0.f, 0.f, 0.f, 0.f, 0.f, 0.f, 0.f, 0.f};
#pragma unroll 4
  for (int i = 0; i < 64; ++i) {
    const float wv = WL[tid * 64 + ((i + tid) & 63)];
#pragma unroll
    for (int je = 0; je < 8; ++je)
      acc[je] += attn[((size_t)bh * 64 + i) * 64 + jb + je] * wv;
  }
#pragma unroll
  for (int je = 0; je < 8; ++je)
    WeT[(size_t)g * 131072 + (size_t)(hh * 64 + jb + je) * 256 + tid] =
        acc[je];
}

__global__ __launch_bounds__(256)
void k5a_part(const float* __restrict__ Wkv, const float* __restrict__ WeT,
              float* __restrict__ Mp) {
  const int bc = blockIdx.x;
  const int oc = blockIdx.y;
  const int g  = blockIdx.z;
  const int tid = threadIdx.x;
  const int b0 = bc * 4;
  const float* __restrict__ Weg = WeT + (size_t)g * 131072;
  float acc[4] = {0.f, 0.f, 0.f, 0.f};
#pragma unroll 8
  for (int u = 0; u < 32; ++u) {
    const int o = oc * 32 + u;
    const float wv = Weg[(size_t)o * 256 + tid];
    const float* __restrict__ vr = Wkv + (size_t)(512 + o) * 256 + b0;
    acc[0] += vr[0] * wv;
    acc[1] += vr[1] * wv;
    acc[2] += vr[2] * wv;
    acc[3] += vr[3] * wv;
  }
#pragma unroll
  for (int be = 0; be < 4; ++be)
    Mp[(((size_t)g * 16 + oc) * 256 + b0 + be) * 256 + tid] = acc[be];
}

__global__ __launch_bounds__(256)
void k5b_red(const float* __restrict__ Mp, float* __restrict__ Mt,
             u16* __restrict__ MA) {
  const int b = blockIdx.x;
  const int g = blockIdx.y;
  const int tid = threadIdx.x;
  const float* __restrict__ P =
      Mp + ((size_t)g * 16 * 256 + b) * 256 + tid;
  float v = 0.f;
#pragma unroll
  for (int oc = 0; oc < 16; ++oc) v += P[(size_t)oc * 65536];
  Mt[(size_t)g * 65536 + (size_t)b * 256 + tid] = v;
  MA[(size_t)g * 65536 + (size_t)tid * 256 + b] = f2bf(v);
}

__global__ __launch_bounds__(256) void k5_serial(const float* __restrict__ Wkv,
                                                 const float* __restrict__ WeT,
                                                 float* __restrict__ Mt,
                                                 u16* __restrict__ MA) {
  const int bc = blockIdx.x;
  const int g  = blockIdx.y;
  const int tid = threadIdx.x;
  const int b0 = bc * 4;
  const float* __restrict__ Weg = WeT + (size_t)g * 131072;
  float acc[4] = {0.f, 0.f, 0.f, 0.f};
#pragma unroll 4
  for (int o = 0; o < 512; ++o) {
    const float wv = Weg[(size_t)o * 256 + tid];
    const float* __restrict__ vr = Wkv + (size_t)(512 + o) * 256 + b0;
    acc[0] += vr[0] * wv;
    acc[1] += vr[1] * wv;
    acc[2] += vr[2] * wv;
    acc[3] += vr[3] * wv;
  }
#pragma unroll
  for (int be = 0; be < 4; ++be) {
    Mt[(size_t)g * 65536 + (size_t)(b0 + be) * 256 + tid] = acc[be];
    MA[(size_t)g * 65536 + (size_t)tid * 256 + b0 + be] = f2bf(acc[be]);
  }
}

// Fallback fp32 K6.
__global__ __launch_bounds__(256)
void k6_apply(const float* __restrict__ x, const float* __restrict__ Mt,
              const float* __restrict__ bout, float* __restrict__ out) {
  __shared__ float As[32 * 132];
  __shared__ float Bs[32 * 132];
  const int pc = blockIdx.x;
  const int oy = blockIdx.y;
  const int g  = blockIdx.z;
  const int p0 = pc * 128;
  const int o0 = oy * 128;
  const float* __restrict__ Xg = x + (size_t)g * 256 * NP;
  const float* __restrict__ Mg = Mt + (size_t)g * 65536;
  const int tid  = threadIdx.x;
  const int lane = tid & 63;
  const int w    = tid >> 6;
  const int wy = (w >> 1) * 64;
  const int wx = (w & 1) * 64;
  const int ly = (lane >> 3) * 8;
  const int lx = (lane & 7) * 8;
  float acc[8][8];
#pragma unroll
  for (int e = 0; e < 8; ++e)
#pragma unroll
    for (int f = 0; f < 8; ++f) acc[e][f] = 0.f;
  const int c4 = (tid & 31) * 4;
  const int kb = tid >> 5;
  for (int s = 0; s < 8; ++s) {
#pragma unroll
    for (int r = 0; r < 4; ++r) {
      const int kk = kb + r * 8;
      const int f  = s * 32 + kk;
      *(float4*)&As[kk * 132 + c4] =
          *(const float4*)(Mg + (size_t)f * 256 + o0 + c4);
      *(float4*)&Bs[kk * 132 + c4] =
          *(const float4*)(Xg + (size_t)f * NP + p0 + c4);
    }
    __syncthreads();
#pragma unroll 4
    for (int kk = 0; kk < 32; ++kk) {
      const float* __restrict__ ar = &As[kk * 132 + wy + ly];
      const float* __restrict__ br = &Bs[kk * 132 + wx + lx];
      float4 a0 = *(const float4*)(ar);
      float4 a1 = *(const float4*)(ar + 4);
      float4 b0 = *(const float4*)(br);
      float4 b1 = *(const float4*)(br + 4);
      const float av[8] = {a0.x, a0.y, a0.z, a0.w, a1.x, a1.y, a1.z, a1.w};
      const float bv[8] = {b0.x, b0.y, b0.z, b0.w, b1.x, b1.y, b1.z, b1.w};
#pragma unroll
      for (int e = 0; e < 8; ++e)
#pragma unroll
        for (int f = 0; f < 8; ++f) acc[e][f] += av[e] * bv[f];
    }
    __syncthreads();
  }
#pragma unroll
  for (int e = 0; e < 8; ++e) {
    const int co = o0 + wy + ly + e;
    const float bo = bout[co];
    float* __restrict__ orow =
        out + ((size_t)(g * 256 + co)) * NP + p0 + wx + lx;
    float4 s0 = {acc[e][0] + bo, acc[e][1] + bo, acc[e][2] + bo,
                 acc[e][3] + bo};
    float4 s1 = {acc[e][4] + bo, acc[e][5] + bo, acc[e][6] + bo,
                 acc[e][7] + bo};
    *(float4*)(orow)     = s0;
    *(float4*)(orow + 4) = s1;
  }
}

// ---------------------------------------------------------------------------
extern "C" void kernel_launch(void* const* d_in, const int* in_sizes, int n_in,
                              void* d_out, int out_size, void* d_ws,
                              size_t ws_size, hipStream_t stream) {
  const float* x    = (const float*)d_in[0];
  const float* Wq   = (const float*)d_in[1];
  const float* Wkv  = (const float*)d_in[2];
  const float* Wout = (const float*)d_in[3];
  const float* bout = (const float*)d_in[4];
  float* out = (float*)d_out;
  float* ws  = (float*)d_ws;

  float* C    = ws + OFF_C;
  float* T    = ws + OFF_T;
  float* att  = ws + OFF_AT;
  float* WeT  = ws + OFF_WE;
  float* Mt   = ws + OFF_MT;
  u16*   MA   = (u16*)(ws + OFF_MA);
  u16*   Xb   = (u16*)(ws + OFF_XB);
  float* Cp1  = ws + OFF_CP1;
  float* Cp2  = ws + OFF_CP2;

  const bool mfma_path = (ws_size >= NEED1);
  const bool splitk    = (ws_size >= NEED2);

  if (mfma_path) {
    // 7-node graph: k0 -> k1 -> k1b -> kA -> kB -> kC -> k6
    k0_cvt<<<dim3(256, 2), 256, 0, stream>>>(x, Xb);
    k1_mfma<<<dim3(4, 32, 2), 256, 0, stream>>>(Xb, Cp1);
    k1b_red<<<dim3(64, 4, 2), 256, 0, stream>>>(Cp1, C);
    kA_attn<<<dim3(16, 16), 256, 0, stream>>>(Wq, Wkv, C, att);
    kB_m<<<dim3(16, 16), 256, 0, stream>>>(Wout, Wkv, att, Cp1);
    kC_red<<<dim3(32, 2), 256, 0, stream>>>(Cp1, MA);
    k6_mfma<<<dim3(128, 2, 2), 256, 0, stream>>>(Xb, MA, bout, out);
    return;
  }

  // Fallback tiers (original chain).
  if (splitk) {
    k1_gram<<<dim3(64, 3, 2), 256, 0, stream>>>(x, Cp2);
    k1b_reduce<<<dim3(64, 3, 2), 256, 0, stream>>>(Cp2, C);
  } else {
    hipMemsetAsync(C, 0, 131072 * sizeof(float), stream);
    k1_gram_atomic<<<dim3(64, 3, 2), 256, 0, stream>>>(x, C);
  }
  k2_T<<<dim3(16, 16), 256, 0, stream>>>(Wq, C, T);
  k3_sim<<<dim3(16, 4), 256, 0, stream>>>(Wkv, T, att);
  k3b_softmax<<<dim3(16), 64, 0, stream>>>(att);
  k4_we<<<dim3(8, 8, 2), 256, 0, stream>>>(Wout, att, WeT);
  if (splitk) {
    k5a_part<<<dim3(64, 16, 2), 256, 0, stream>>>(Wkv, WeT, Cp2);
    k5b_red<<<dim3(256, 2), 256, 0, stream>>>(Cp2, Mt, MA);
  } else {
    k5_serial<<<dim3(64, 2), 256, 0, stream>>>(Wkv, WeT, Mt, MA);
  }
  k6_apply<<<dim3(128, 2, 2), 256, 0, stream>>>(x, Mt, bout, out);
}